// Round 10
// baseline (337.768 us; speedup 1.0000x reference)
//
#include <hip/hip_runtime.h>
#include <hip/hip_bf16.h>

// Problem constants
#define Bq   16
#define Nq   1024
#define Cq   256
#define NHq  8
#define DHq  32
#define HIDq 1024
#define BNq  (Bq * Nq)   // 16384 tokens

typedef float f32x4 __attribute__((ext_vector_type(4)));
typedef short bf16x8 __attribute__((ext_vector_type(8)));
typedef unsigned short ushort_t;

__device__ __forceinline__ unsigned int f2bf(float f) {   // RNE
    unsigned int u = __builtin_bit_cast(unsigned int, f);
    u = (u + 0x7fffu + ((u >> 16) & 1u)) >> 16;
    return u & 0xffffu;
}
// pack two floats -> two bf16 (round-half-up) in one dword via v_perm
__device__ __forceinline__ unsigned int packbf2(float a, float b) {
    unsigned int ua = __builtin_bit_cast(unsigned int, a) + 0x8000u;
    unsigned int ub = __builtin_bit_cast(unsigned int, b) + 0x8000u;
    return __builtin_amdgcn_perm(ub, ua, 0x07060302);
}
// single-instruction packed f32x2 -> bf16x2 (RNE); lo -> low half
__device__ __forceinline__ unsigned int cvtpk_bf16(float lo, float hi) {
    unsigned int r;
    asm("v_cvt_pk_bf16_f32 %0, %1, %2" : "=v"(r) : "v"(lo), "v"(hi));
    return r;
}
// branch-free tanh-approx GELU
__device__ __forceinline__ float gelu_t(float x) {
    float y = x * (0.7978845608028654f + 0.035677408136300125f * x * x);
    float e = __builtin_amdgcn_exp2f(y * 2.8853900817779268f);
    return x - x / (1.f + e);
}

typedef __attribute__((address_space(1))) const unsigned int* gas_u32;
typedef __attribute__((address_space(3))) unsigned int* las_u32;
__device__ __forceinline__ void gload16(const void* g, void* l) {
    __builtin_amdgcn_global_load_lds((gas_u32)g, (las_u32)l, 16, 0, 0);
}

// ---------------------------------------------------------------------------
// Fused fp32 -> bf16 casts: 9 segments in one dispatch.
// ---------------------------------------------------------------------------
struct CastSeg { const float* src; ushort_t* dst; int nblk; int n; };
struct CastArgs { CastSeg s[9]; };

__global__ __launch_bounds__(256) void castm(CastArgs a) {
    int bid = blockIdx.x;
    int seg = 0, acc = 0;
    for (seg = 0; seg < 9; seg++) {
        if (bid < acc + a.s[seg].nblk) break;
        acc += a.s[seg].nblk;
    }
    const CastSeg sg = a.s[seg];
    int i = (bid - acc) * 1024 + threadIdx.x * 4;
    if (i < sg.n) {
        float4 v = *(const float4*)(sg.src + i);
        uint2 u;
        u.x = packbf2(v.x, v.y);
        u.y = packbf2(v.z, v.w);
        *(uint2*)(sg.dst + i) = u;
    }
}

// ---------------------------------------------------------------------------
// LayerNorm over C=256 -> bf16. One wave per token, 4 tokens per block.
// ---------------------------------------------------------------------------
__global__ __launch_bounds__(256) void ln_kernel(const float* __restrict__ X,
                                                 const float* __restrict__ w,
                                                 const float* __restrict__ b,
                                                 ushort_t* __restrict__ Y) {
    int wave = threadIdx.x >> 6, lane = threadIdx.x & 63;
    int t = blockIdx.x * 4 + wave;
    float4 v = *(const float4*)(X + (size_t)t * Cq + lane * 4);
    float s = v.x + v.y + v.z + v.w;
#pragma unroll
    for (int d = 1; d < 64; d <<= 1) s += __shfl_xor(s, d);
    float mean = s * (1.f / 256.f);
    float4 dv = {v.x - mean, v.y - mean, v.z - mean, v.w - mean};
    float q = dv.x * dv.x + dv.y * dv.y + dv.z * dv.z + dv.w * dv.w;
#pragma unroll
    for (int d = 1; d < 64; d <<= 1) q += __shfl_xor(q, d);
    float rs = rsqrtf(q * (1.f / 256.f) + 1e-5f);
    float4 wv = *(const float4*)(w + lane * 4);
    float4 bv = *(const float4*)(b + lane * 4);
    uint2 u;
    u.x = packbf2(dv.x * rs * wv.x + bv.x, dv.y * rs * wv.y + bv.y);
    u.y = packbf2(dv.z * rs * wv.z + bv.z, dv.w * rs * wv.w + bv.w);
    *(uint2*)(Y + (size_t)t * Cq + lane * 4) = u;
}

// ---------------------------------------------------------------------------
// MFMA GEMM with counted-vmcnt double-buffered pipeline (R4 structure —
// measured best for the small projection GEMMs).
// BM=128, BN=64, BK=64; 4 waves, wave w owns rows [w*32, w*32+32).
// LDS: A 2x16KB, B 2x8KB = 48KB. Fragment-ordered chunks: chunk c (0..7)
// holds k=(c&3)*8+(c>>2)*32; wave w stages chunks {w, w+4}.
// Per iter t (cur=t&1): ds_read 12 frags(cur) -> lgkm(0) -> barrier ->
// STAGE(cur, t+2) -> 16 MFMA -> vmcnt(6) [waits only tile t+1] -> barrier.
// MFMA operands swapped (C^T): thread holds 4 consecutive n-values.
// OMODE 0: fp32 out (+bias/residual); OMODE 1: qkv -> bf16 head-major
//          (Q scaled by rsqrt(32)*log2e, V transposed [bh][32][1024]);
// OMODE 2: bf16 out; OMODE 3: fused off/aw (ng<64 -> OffB w/ bias, else AwB
//          w/ R-as-bias; AwB = OutP + BN*64).
// ---------------------------------------------------------------------------
template <int OMODE, bool GELU_, bool RESID, int KT>
__global__ __launch_bounds__(256) void mgemm(const ushort_t* __restrict__ A,
                                             const ushort_t* __restrict__ W,
                                             const float* __restrict__ bias,
                                             const float* __restrict__ R,
                                             void* __restrict__ OutP,
                                             int M, int Nn) {
    __shared__ __align__(16) ushort_t Al[2][8192];
    __shared__ __align__(16) ushort_t Bl[2][4096];
    int m0 = blockIdx.x * 128, n0 = blockIdx.y * 64;
    int tid = threadIdx.x;
    int w = tid >> 6, lane = tid & 63;
    int l15 = lane & 15, quad = lane >> 4;

    f32x4 acc[2][4];
#pragma unroll
    for (int i = 0; i < 2; i++)
#pragma unroll
        for (int j = 0; j < 4; j++) acc[i][j] = (f32x4){0.f, 0.f, 0.f, 0.f};

    const ushort_t* gA0 = A + (size_t)(m0 + lane) * KT + w * 8;
    const ushort_t* gA1 = gA0 + (size_t)64 * KT;
    const ushort_t* gB0 = W + (size_t)(n0 + lane) * KT + w * 8;

    auto STAGE = [&](int buf, int t) {
        const int k0 = t * 64;
        gload16(gA0 + k0,      &Al[buf][w * 1024]);
        gload16(gA1 + k0,      &Al[buf][w * 1024 + 512]);
        gload16(gA0 + k0 + 32, &Al[buf][(w + 4) * 1024]);
        gload16(gA1 + k0 + 32, &Al[buf][(w + 4) * 1024 + 512]);
        gload16(gB0 + k0,      &Bl[buf][w * 512]);
        gload16(gB0 + k0 + 32, &Bl[buf][(w + 4) * 512]);
    };

    constexpr int NT = KT / 64;
    STAGE(0, 0);
    STAGE(1, 1);
    asm volatile("s_waitcnt vmcnt(6)" ::: "memory");   // tile 0 landed
    __builtin_amdgcn_s_barrier();

#pragma unroll
    for (int t = 0; t < NT; t++) {
        const int cur = t & 1;
        bf16x8 aF[2][2], bF[2][4];
#pragma unroll
        for (int ks = 0; ks < 2; ks++) {
#pragma unroll
            for (int i = 0; i < 2; i++)
                aF[ks][i] = *(const bf16x8*)&Al[cur][(ks * 4 + quad) * 1024 + (w * 32 + i * 16 + l15) * 8];
#pragma unroll
            for (int j = 0; j < 4; j++)
                bF[ks][j] = *(const bf16x8*)&Bl[cur][(ks * 4 + quad) * 512 + (j * 16 + l15) * 8];
        }
        asm volatile("s_waitcnt lgkmcnt(0)" ::: "memory");
        __builtin_amdgcn_sched_barrier(0);
        __builtin_amdgcn_s_barrier();        // all waves done reading cur
        if (t + 2 < NT) STAGE(cur, t + 2);

        __builtin_amdgcn_s_setprio(1);
#pragma unroll
        for (int ks = 0; ks < 2; ks++)
#pragma unroll
            for (int i = 0; i < 2; i++)
#pragma unroll
                for (int j = 0; j < 4; j++)
                    acc[i][j] = __builtin_amdgcn_mfma_f32_16x16x32_bf16(bF[ks][j], aF[ks][i], acc[i][j], 0, 0, 0);
        __builtin_amdgcn_s_setprio(0);

        if (t + 2 < NT) {
            asm volatile("s_waitcnt vmcnt(6)" ::: "memory");
        } else if (t + 1 < NT) {
            asm volatile("s_waitcnt vmcnt(0)" ::: "memory");
        }
        if (t + 1 < NT) __builtin_amdgcn_s_barrier();
    }

#pragma unroll
    for (int i = 0; i < 2; i++) {
        int mg = m0 + w * 32 + i * 16 + l15;
#pragma unroll
        for (int j = 0; j < 4; j++) {
            int ng = n0 + j * 16 + quad * 4;
            f32x4 rv = acc[i][j];
            if constexpr (OMODE == 1) {
                int which = ng >> 8;
                int h = (ng >> 5) & 7;
                int d = ng & 31;
                int bb = mg >> 10, nn = mg & 1023;
                ushort_t* qb = (ushort_t*)OutP;
                if (which == 2) {          // V transposed: [bh][d][n]
                    size_t dst = 2 * (size_t)BNq * Cq +
                                 ((size_t)(bb * 8 + h) * 32 + d) * 1024 + nn;
#pragma unroll
                    for (int r = 0; r < 4; r++)
                        qb[dst + (size_t)r * 1024] = (ushort_t)f2bf(rv[r]);
                } else {
                    if (which == 0) {
                        const float sc = 0.17677669529663687f * 1.4426950408889634f;
                        rv[0] *= sc; rv[1] *= sc; rv[2] *= sc; rv[3] *= sc;
                    }
                    size_t dst = (size_t)which * ((size_t)BNq * Cq) +
                                 ((size_t)(bb * 8 + h) * 1024 + nn) * 32 + d;
                    uint2 pk;
                    pk.x = packbf2(rv[0], rv[1]);
                    pk.y = packbf2(rv[2], rv[3]);
                    *(uint2*)(qb + dst) = pk;
                }
            } else if constexpr (OMODE == 3) {
                if (ng >= 96) continue;
                if (ng < 64) {
                    float4 bv = *(const float4*)(bias + ng);
                    rv[0] += bv.x; rv[1] += bv.y; rv[2] += bv.z; rv[3] += bv.w;
                    *(float4*)((float*)OutP + (size_t)mg * 64 + ng) =
                        make_float4(rv[0], rv[1], rv[2], rv[3]);
                } else {
                    float4 bv = *(const float4*)(R + (ng - 64));
                    rv[0] += bv.x; rv[1] += bv.y; rv[2] += bv.z; rv[3] += bv.w;
                    *(float4*)((float*)OutP + (size_t)BNq * 64 + (size_t)mg * 32 + (ng - 64)) =
                        make_float4(rv[0], rv[1], rv[2], rv[3]);
                }
            } else {
                if (bias) {
                    float4 bv = *(const float4*)(bias + ng);
                    rv[0] += bv.x; rv[1] += bv.y; rv[2] += bv.z; rv[3] += bv.w;
                }
                if (GELU_) {
#pragma unroll
                    for (int r = 0; r < 4; r++) rv[r] = gelu_t(rv[r]);
                }
                if constexpr (OMODE == 2) {
                    uint2 pk;
                    pk.x = packbf2(rv[0], rv[1]);
                    pk.y = packbf2(rv[2], rv[3]);
                    *(uint2*)((ushort_t*)OutP + (size_t)mg * Nn + ng) = pk;
                } else {
                    if (RESID) {
                        float4 rr = *(const float4*)(R + (size_t)mg * Nn + ng);
                        rv[0] += rr.x; rv[1] += rr.y; rv[2] += rr.z; rv[3] += rr.w;
                    }
                    *(float4*)((float*)OutP + (size_t)mg * Nn + ng) =
                        make_float4(rv[0], rv[1], rv[2], rv[3]);
                }
            }
        }
    }
}

// ---------------------------------------------------------------------------
// Fused MLP v2: out = X + gelu(Y @ W1^T + b1) @ W2^T + b2, H never leaves LDS.
// SINGLE-buffered W1/W2 -> LDS 76KB (W1 32 + W2 32 + H 8 + b1 4) -> 2
// blocks/CU co-resident (was 108KB/1 block/CU: every stall exposed; the
// attn kernel proves cross-block overlap is the working mechanism here).
// Block = 64 m-rows (grid 256 = 2 blocks/CU in flight), 4 waves, 16
// hid-chunks of 64. A (Y rows) in registers. Counted-vmcnt ledger (8 loads
// per SW group), traced incl. prologue and tail:
//   GEMM1(W1l,aF) -> bias+gelu -> H ds_write -> lgkm(0) -> B1 [W1l free, H
//   visible] -> SW1(ch+1) -> vmcnt(8) [drains SW2(ch), issued a full chunk
//   ago] -> B2 [W2[ch] visible] -> GEMM2 (Hl x W2l -> acc2) -> lgkm(0) ->
//   B3 [W2l+H free] -> SW2(ch+1) -> vmcnt(8) [drains SW1(ch+1), covered by
//   GEMM2] -> B4 [W1[ch+1] visible]. Tail: vmcnt(0) at B2 when no SW1.
// Layouts (fragment-ordered 8-k chunks, chunk c holds k=(c&3)*8+(c>>2)*32):
//   W1l: [kc 0..31][row h 0..63][8]   addr kc*512+row*8
//   W2l: [kc2 0..7][row n 0..255][8]  addr kc2*2048+row*8
//   Hl : [kh 0..7][row m 0..63][8]    addr kh*512+row*8
// ---------------------------------------------------------------------------
__global__ __launch_bounds__(256) void mlp_fused(const ushort_t* __restrict__ Y,
                                                 const ushort_t* __restrict__ W1,
                                                 const float* __restrict__ b1,
                                                 const ushort_t* __restrict__ W2,
                                                 const float* __restrict__ b2,
                                                 const float* __restrict__ Xr,
                                                 float* __restrict__ out) {
    __shared__ __align__(16) ushort_t W1l[16384];      // 32 KB
    __shared__ __align__(16) ushort_t W2l[16384];      // 32 KB
    __shared__ __align__(16) ushort_t Hl[4096];        // 8 KB
    __shared__ __align__(16) float b1l[1024];          // 4 KB
    int m0 = blockIdx.x * 64;
    int tid = threadIdx.x;
    int w = tid >> 6, lane = tid & 63;
    int l15 = lane & 15, quad = lane >> 4;

    // A rows in registers: row = m0 + w*16 + l15, k = ks*32 + quad*8
    bf16x8 aF[8];
    {
        const ushort_t* ga = Y + (size_t)(m0 + w * 16 + l15) * 256 + quad * 8;
#pragma unroll
        for (int ks = 0; ks < 8; ks++) aF[ks] = *(const bf16x8*)(ga + ks * 32);
    }

    // stage W1 chunk ch (64 h-rows x 256 k): wave w stages kc = w + 4j
    auto SW1 = [&](int ch) {
        const ushort_t* g = W1 + (size_t)(ch * 64 + lane) * 256 + w * 8;
#pragma unroll
        for (int j = 0; j < 8; j++)
            gload16(g + j * 32, &W1l[(w + 4 * j) * 512]);
    };
    // stage W2 chunk ch (256 n-rows x 64 hid): wave w stages kc2 = {w, w+4}
    auto SW2 = [&](int ch) {
#pragma unroll
        for (int jj = 0; jj < 8; jj++) {
            const int kc2 = (jj & 1) * 4 + w;
            const int rj = jj >> 1;              // n-row group of 64
            const ushort_t* g = W2 + (size_t)(rj * 64 + lane) * 1024 + ch * 64 +
                                (kc2 & 3) * 8 + (kc2 >> 2) * 32;
            gload16(g, &W2l[kc2 * 2048 + rj * 512]);
        }
    };

    f32x4 acc2[4][4];
#pragma unroll
    for (int i = 0; i < 4; i++)
#pragma unroll
        for (int j = 0; j < 4; j++) acc2[i][j] = (f32x4){0.f, 0.f, 0.f, 0.f};

    // prologue: stage chunk 0 of both weights + bias, full drain once.
    SW1(0);
    SW2(0);
    gload16(b1 + w * 256 + lane * 4, &b1l[w * 256]);   // bias -> LDS
    asm volatile("s_waitcnt vmcnt(0)" ::: "memory");
    __builtin_amdgcn_s_barrier();

    for (int ch = 0; ch < 16; ch++) {
        // ---- GEMM1: H(64x64) = A(64x256) @ W1[ch]^T ----
        f32x4 acc1[4];
#pragma unroll
        for (int j = 0; j < 4; j++) acc1[j] = (f32x4){0.f, 0.f, 0.f, 0.f};
#pragma unroll
        for (int ks = 0; ks < 8; ks++) {
            bf16x8 bF[4];
#pragma unroll
            for (int j = 0; j < 4; j++)
                bF[j] = *(const bf16x8*)&W1l[(ks * 4 + quad) * 512 + (j * 16 + l15) * 8];
#pragma unroll
            for (int j = 0; j < 4; j++)
                acc1[j] = __builtin_amdgcn_mfma_f32_16x16x32_bf16(bF[j], aF[ks], acc1[j], 0, 0, 0);
        }
        // ---- bias + gelu -> H LDS (GEMM2-fragment order) ----
#pragma unroll
        for (int j = 0; j < 4; j++) {
            float4 b1v = *(const float4*)&b1l[ch * 64 + j * 16 + quad * 4];
            f32x4 rv = acc1[j];
            rv[0] = gelu_t(rv[0] + b1v.x);
            rv[1] = gelu_t(rv[1] + b1v.y);
            rv[2] = gelu_t(rv[2] + b1v.z);
            rv[3] = gelu_t(rv[3] + b1v.w);
            int h = j * 16 + quad * 4;
            uint2 pk;
            pk.x = cvtpk_bf16(rv[0], rv[1]);
            pk.y = cvtpk_bf16(rv[2], rv[3]);
            *(uint2*)&Hl[((h >> 3) * 64 + (w * 16 + l15)) * 8 + (h & 7)] = pk;
        }
        asm volatile("s_waitcnt lgkmcnt(0)" ::: "memory");  // W1 reads + H writes done
        __builtin_amdgcn_sched_barrier(0);
        __builtin_amdgcn_s_barrier();          // B1: W1l free; H visible
        if (ch + 1 < 16) {
            SW1(ch + 1);                        // overwrite W1l for next chunk
            asm volatile("s_waitcnt vmcnt(8)" ::: "memory"); // SW2(ch) landed
        } else {
            asm volatile("s_waitcnt vmcnt(0)" ::: "memory");
        }
        __builtin_amdgcn_s_barrier();          // B2: W2[ch] visible to all

        // ---- GEMM2: acc2 += H(64x64) @ W2[ch]^T (wave w owns n [w*64,+64)) ----
        __builtin_amdgcn_s_setprio(1);
#pragma unroll
        for (int ks2 = 0; ks2 < 2; ks2++) {
            bf16x8 a2[4], b2f[4];
#pragma unroll
            for (int i = 0; i < 4; i++)
                a2[i] = *(const bf16x8*)&Hl[(ks2 * 4 + quad) * 512 + (i * 16 + l15) * 8];
#pragma unroll
            for (int j = 0; j < 4; j++)
                b2f[j] = *(const bf16x8*)&W2l[(ks2 * 4 + quad) * 2048 + (w * 64 + j * 16 + l15) * 8];
#pragma unroll
            for (int i = 0; i < 4; i++)
#pragma unroll
                for (int j = 0; j < 4; j++)
                    acc2[i][j] = __builtin_amdgcn_mfma_f32_16x16x32_bf16(b2f[j], a2[i], acc2[i][j], 0, 0, 0);
        }
        __builtin_amdgcn_s_setprio(0);
        asm volatile("s_waitcnt lgkmcnt(0)" ::: "memory");  // W2/H reads retired
        __builtin_amdgcn_sched_barrier(0);
        __builtin_amdgcn_s_barrier();          // B3: W2l + Hl free
        if (ch + 1 < 16) {
            SW2(ch + 1);                        // overwrite W2l for next chunk
            asm volatile("s_waitcnt vmcnt(8)" ::: "memory"); // SW1(ch+1) landed
            __builtin_amdgcn_s_barrier();      // B4: W1[ch+1] visible to all
        }
    }

    // ---- epilogue: out = acc2 + b2 + X ----
#pragma unroll
    for (int i = 0; i < 4; i++) {
        int mg = m0 + i * 16 + l15;
#pragma unroll
        for (int j = 0; j < 4; j++) {
            int ng = w * 64 + j * 16 + quad * 4;
            f32x4 rv = acc2[i][j];
            float4 bv = *(const float4*)(b2 + ng);
            float4 rr = *(const float4*)(Xr + (size_t)mg * 256 + ng);
            rv[0] += bv.x + rr.x; rv[1] += bv.y + rr.y;
            rv[2] += bv.z + rr.z; rv[3] += bv.w + rr.w;
            *(float4*)(out + (size_t)mg * 256 + ng) =
                make_float4(rv[0], rv[1], rv[2], rv[3]);
        }
    }
}

// ---------------------------------------------------------------------------
// MFMA flash attention v2 (unchanged from R4).
// ---------------------------------------------------------------------------
__global__ __launch_bounds__(256, 4) void attn_mfma(const ushort_t* __restrict__ Qb,
                                                    const ushort_t* __restrict__ Kb,
                                                    const ushort_t* __restrict__ Vtg,
                                                    ushort_t* __restrict__ o) {
    int bh = blockIdx.x;
    int b = bh >> 3, h = bh & 7;
    int q0 = blockIdx.y * 128;
    int tid = threadIdx.x;
    int wave = tid >> 6, lane = tid & 63;
    int l15 = lane & 15, quad = lane >> 4;

    __shared__ __align__(16) ushort_t Ks[2][64][40];     // [buf][key][d]
    __shared__ __align__(16) ushort_t Vs[2][32][88];     // [buf][d][key]
    __shared__ __align__(16) ushort_t Ps[4][32][72];     // per wave [q][key]

    const size_t hb = (size_t)bh * 32768;

    bf16x8 qfrag[2];
#pragma unroll
    for (int g = 0; g < 2; g++)
        qfrag[g] = *(const bf16x8*)(Qb + hb + (size_t)(q0 + wave * 32 + g * 16 + l15) * 32 + quad * 8);

    f32x4 oa[2][2];
#pragma unroll
    for (int g = 0; g < 2; g++)
#pragma unroll
        for (int t = 0; t < 2; t++) oa[g][t] = (f32x4){0.f, 0.f, 0.f, 0.f};
    f32x4 ls[2];
    ls[0] = (f32x4){0.f, 0.f, 0.f, 0.f};
    ls[1] = (f32x4){0.f, 0.f, 0.f, 0.f};

    bf16x8 ones;
#pragma unroll
    for (int i = 0; i < 8; i++) ones[i] = (short)0x3F80;   // bf16 1.0

    int krow = tid >> 2, kch = tid & 3;
    int vrow = tid >> 3, vch = tid & 7;
    const ushort_t* kgp = Kb + hb + (size_t)krow * 32 + kch * 8;
    const ushort_t* vgp = Vtg + hb + (size_t)vrow * 1024 + vch * 8;

    // prefetch tile 0 into registers
    bf16x8 kreg = *(const bf16x8*)kgp;
    bf16x8 vreg = *(const bf16x8*)vgp;

#pragma unroll 2
    for (int kt = 0; kt < 16; kt++) {
        const int cur = kt & 1;
        *(bf16x8*)&Ks[cur][krow][kch * 8] = kreg;
        *(bf16x8*)&Vs[cur][vrow][vch * 8] = vreg;
        __syncthreads();
        if (kt < 15) {
            kreg = *(const bf16x8*)(kgp + (kt + 1) * 2048);
            vreg = *(const bf16x8*)(vgp + (kt + 1) * 64);
        }

        bf16x8 kf[4];
#pragma unroll
        for (int kg = 0; kg < 4; kg++)
            kf[kg] = *(const bf16x8*)&Ks[cur][kg * 16 + l15][quad * 8];

        const f32x4 z = {0.f, 0.f, 0.f, 0.f};
#pragma unroll
        for (int g = 0; g < 2; g++) {
#pragma unroll
            for (int kg = 0; kg < 4; kg++) {
                f32x4 st = __builtin_amdgcn_mfma_f32_16x16x32_bf16(kf[kg], qfrag[g], z, 0, 0, 0);
                float e0 = __builtin_amdgcn_exp2f(st[0]);
                float e1 = __builtin_amdgcn_exp2f(st[1]);
                float e2 = __builtin_amdgcn_exp2f(st[2]);
                float e3 = __builtin_amdgcn_exp2f(st[3]);
                uint2 pk;
                pk.x = cvtpk_bf16(e0, e1);
                pk.y = cvtpk_bf16(e2, e3);
                *(uint2*)&Ps[wave][g * 16 + l15][kg * 16 + quad * 4] = pk;
            }
        }

        __builtin_amdgcn_s_setprio(1);
#pragma unroll
        for (int c = 0; c < 2; c++) {
            bf16x8 vb0 = *(const bf16x8*)&Vs[cur][l15][c * 32 + quad * 8];
            bf16x8 vb1 = *(const bf16x8*)&Vs[cur][16 + l15][c * 32 + quad * 8];
#pragma unroll
            for (int g = 0; g < 2; g++) {
                bf16x8 pa = *(const bf16x8*)&Ps[wave][g * 16 + l15][c * 32 + quad * 8];
                oa[g][0] = __builtin_amdgcn_mfma_f32_16x16x32_bf16(pa, vb0, oa[g][0], 0, 0, 0);
                oa[g][1] = __builtin_amdgcn_mfma_f32_16x16x32_bf16(pa, vb1, oa[g][1], 0, 0, 0);
                ls[g]    = __builtin_amdgcn_mfma_f32_16x16x32_bf16(pa, ones, ls[g], 0, 0, 0);
            }
        }
        __builtin_amdgcn_s_setprio(0);
    }

#pragma unroll
    for (int g = 0; g < 2; g++) {
#pragma unroll
        for (int r = 0; r < 4; r++) {
            float inv = 1.f / ls[g][r];
            int q = q0 + wave * 32 + g * 16 + quad * 4 + r;
            ushort_t* orow = o + ((size_t)(b * 1024 + q)) * 256 + h * 32;
            orow[l15] = (ushort_t)f2bf(oa[g][0][r] * inv);
            orow[l15 + 16] = (ushort_t)f2bf(oa[g][1][r] * inv);
        }
    }
}

// ---------------------------------------------------------------------------
// Deformable gather -> bf16. One block per token, thread = (h=tid>>5, d=tid&31).
// ---------------------------------------------------------------------------
__global__ __launch_bounds__(256) void deform_kernel(const float* __restrict__ ref,
                                                     const float* __restrict__ off,
                                                     const float* __restrict__ awl,
                                                     const float* __restrict__ v,
                                                     ushort_t* __restrict__ out) {
    int t = blockIdx.x;
    int b = t >> 10;
    int tid = threadIdx.x;
    int h = tid >> 5, d = tid & 31;

    float rx = ref[(size_t)t * 2 + 0];
    float ry = ref[(size_t)t * 2 + 1];
    const float* offr = off + (size_t)t * 64 + h * 8;
    const float* awr = awl + (size_t)t * 32 + h * 4;

    float L0 = awr[0], L1 = awr[1], L2 = awr[2], L3 = awr[3];
    float mm = fmaxf(fmaxf(L0, L1), fmaxf(L2, L3));
    float e0 = __expf(L0 - mm), e1 = __expf(L1 - mm), e2 = __expf(L2 - mm), e3 = __expf(L3 - mm);
    float inv = 1.f / (e0 + e1 + e2 + e3);
    float aw[4] = {e0 * inv, e1 * inv, e2 * inv, e3 * inv};

    const float* vb = v + (size_t)b * Nq * Cq + h * 32 + d;

    float s = 0.f;
#pragma unroll
    for (int p = 0; p < 4; p++) {
        float gx = rx * 32.f + offr[p * 2 + 0] - 0.5f;
        float gy = ry * 32.f + offr[p * 2 + 1] - 0.5f;
        float x0f = floorf(gx), y0f = floorf(gy);
        float lx = gx - x0f, ly = gy - y0f;
        int x0 = (int)x0f, y0 = (int)y0f;
        auto g = [&](int xi, int yi) -> float {
            if (xi < 0 || xi > 31 || yi < 0 || yi > 31) return 0.f;
            return vb[(size_t)(yi * 32 + xi) * Cq];
        };
        float sp = g(x0, y0) * (1.f - lx) * (1.f - ly)
                 + g(x0 + 1, y0) * lx * (1.f - ly)
                 + g(x0, y0 + 1) * (1.f - lx) * ly
                 + g(x0 + 1, y0 + 1) * lx * ly;
        s += aw[p] * sp;
    }
    out[(size_t)t * Cq + h * 32 + d] = (ushort_t)f2bf(s);
}

// ---------------------------------------------------------------------------
// Launch
// ---------------------------------------------------------------------------
extern "C" void kernel_launch(void* const* d_in, const int* in_sizes, int n_in,
                              void* d_out, int out_size, void* d_ws, size_t ws_size,
                              hipStream_t stream) {
    const size_t S = (size_t)BNq * Cq;  // 4,194,304
    float* ws = (float*)d_ws;
    float* X = ws;                                  // [0, S) residual fp32
    ushort_t* Ybf = (ushort_t*)(ws + S);            // [S, 1.5S)
    ushort_t* Wbf = (ushort_t*)(ws + S + S / 2);    // [1.5S, 2S)

    ushort_t* Wqkv   = Wbf;
    ushort_t* Wproj  = Wbf + 196608;
    ushort_t* Woff   = Wbf + 262144;   // off(64 rows) + aw(32 rows) contiguous
    ushort_t* Waw    = Wbf + 278528;
    ushort_t* Wvproj = Wbf + 286720;
    ushort_t* Woproj = Wbf + 352256;
    ushort_t* Wfc1   = Wbf + 417792;
    ushort_t* Wfc2   = Wbf + 679936;

    ushort_t* QKVbf = (ushort_t*)(ws + 2 * S);              // Q,K,V^T: [2S, 3.5S)
    ushort_t* O1bf  = (ushort_t*)(ws + 2 * S + 3 * S / 2);  // [3.5S, 4S)
    float* Vb   = ws + 2 * S + S / 2;                       // [2.5S, 3.5S)
    float* OffB = ws + 2 * S + 3 * S / 2;                   // [3.5S, 3.75S)
    float* AwB  = OffB + (size_t)BNq * 64;                  // [3.75S, 3.875S)
    ushort_t* Sbbf = (ushort_t*)(AwB + (size_t)BNq * 32);   // [3.875S, 4.375S)
    ushort_t* Valbf = (ushort_t*)(ws + 9 * S / 2);          // [4.5S, 5S)

    auto fp = [&](int i) { return (const float*)d_in[i]; };
    const float* x_in = fp(0);

    // ---- all fp32->bf16 casts in one dispatch ----
    CastArgs ca;
    ca.s[0] = {fp(9),  Wqkv,   192, 196608};
    ca.s[1] = {fp(10), Wproj,  64,  65536};
    ca.s[2] = {fp(12), Woff,   16,  16384};
    ca.s[3] = {fp(14), Waw,    8,   8192};
    ca.s[4] = {fp(16), Wvproj, 64,  65536};
    ca.s[5] = {fp(18), Woproj, 64,  65536};
    ca.s[6] = {fp(20), Wfc1,   256, 262144};
    ca.s[7] = {fp(22), Wfc2,   256, 262144};
    ca.s[8] = {fp(2),  Valbf,  4096, (int)S};
    castm<<<5016, 256, 0, stream>>>(ca);

    // ---- stage 1: self-attention ----
    ln_kernel<<<BNq / 4, 256, 0, stream>>>(x_in, fp(3), fp(4), Ybf);
    mgemm<1, false, false, 256><<<dim3(128, 12), 256, 0, stream>>>(
        Ybf, Wqkv, nullptr, nullptr, QKVbf, BNq, 768);
    attn_mfma<<<dim3(128, 8), 256, 0, stream>>>(
        QKVbf, QKVbf + S, QKVbf + 2 * S, O1bf);
    mgemm<0, false, true, 256><<<dim3(128, 4), 256, 0, stream>>>(
        O1bf, Wproj, fp(11), x_in, X, BNq, 256);

    // ---- stage 2: deformable attention ----
    ln_kernel<<<BNq / 4, 256, 0, stream>>>(X, fp(5), fp(6), Ybf);
    mgemm<0, false, false, 256><<<dim3(128, 4), 256, 0, stream>>>(
        Valbf, Wvproj, fp(17), nullptr, Vb, BNq, 256);
    mgemm<3, false, false, 256><<<dim3(128, 2), 256, 0, stream>>>(
        Ybf, Woff, fp(13), fp(15), OffB, BNq, 96);
    deform_kernel<<<BNq, 256, 0, stream>>>(fp(1), OffB, AwB, Vb, Sbbf);
    mgemm<0, false, true, 256><<<dim3(128, 4), 256, 0, stream>>>(
        Sbbf, Woproj, fp(19), X, X, BNq, 256);

    // ---- stage 3: MLP (fused fc1+gelu+fc2+residual; H stays in LDS) ----
    ln_kernel<<<BNq / 4, 256, 0, stream>>>(X, fp(7), fp(8), Ybf);
    mlp_fused<<<BNq / 64, 256, 0, stream>>>(
        Ybf, Wfc1, fp(21), Wfc2, fp(23), X, (float*)d_out);
}

// Round 11
// 323.946 us; speedup vs baseline: 1.0427x; 1.0427x over previous
//
#include <hip/hip_runtime.h>
#include <hip/hip_bf16.h>

// Problem constants
#define Bq   16
#define Nq   1024
#define Cq   256
#define NHq  8
#define DHq  32
#define HIDq 1024
#define BNq  (Bq * Nq)   // 16384 tokens

typedef float f32x4 __attribute__((ext_vector_type(4)));
typedef short bf16x8 __attribute__((ext_vector_type(8)));
typedef unsigned short ushort_t;

__device__ __forceinline__ unsigned int f2bf(float f) {   // RNE
    unsigned int u = __builtin_bit_cast(unsigned int, f);
    u = (u + 0x7fffu + ((u >> 16) & 1u)) >> 16;
    return u & 0xffffu;
}
// pack two floats -> two bf16 (round-half-up) in one dword via v_perm
__device__ __forceinline__ unsigned int packbf2(float a, float b) {
    unsigned int ua = __builtin_bit_cast(unsigned int, a) + 0x8000u;
    unsigned int ub = __builtin_bit_cast(unsigned int, b) + 0x8000u;
    return __builtin_amdgcn_perm(ub, ua, 0x07060302);
}
// single-instruction packed f32x2 -> bf16x2 (RNE); lo -> low half
__device__ __forceinline__ unsigned int cvtpk_bf16(float lo, float hi) {
    unsigned int r;
    asm("v_cvt_pk_bf16_f32 %0, %1, %2" : "=v"(r) : "v"(lo), "v"(hi));
    return r;
}
// branch-free tanh-approx GELU
__device__ __forceinline__ float gelu_t(float x) {
    float y = x * (0.7978845608028654f + 0.035677408136300125f * x * x);
    float e = __builtin_amdgcn_exp2f(y * 2.8853900817779268f);
    return x - x / (1.f + e);
}

typedef __attribute__((address_space(1))) const unsigned int* gas_u32;
typedef __attribute__((address_space(3))) unsigned int* las_u32;
__device__ __forceinline__ void gload16(const void* g, void* l) {
    __builtin_amdgcn_global_load_lds((gas_u32)g, (las_u32)l, 16, 0, 0);
}

// ---------------------------------------------------------------------------
// Fused fp32 -> bf16 casts: 9 segments in one dispatch.
// ---------------------------------------------------------------------------
struct CastSeg { const float* src; ushort_t* dst; int nblk; int n; };
struct CastArgs { CastSeg s[9]; };

__global__ __launch_bounds__(256) void castm(CastArgs a) {
    int bid = blockIdx.x;
    int seg = 0, acc = 0;
    for (seg = 0; seg < 9; seg++) {
        if (bid < acc + a.s[seg].nblk) break;
        acc += a.s[seg].nblk;
    }
    const CastSeg sg = a.s[seg];
    int i = (bid - acc) * 1024 + threadIdx.x * 4;
    if (i < sg.n) {
        float4 v = *(const float4*)(sg.src + i);
        uint2 u;
        u.x = packbf2(v.x, v.y);
        u.y = packbf2(v.z, v.w);
        *(uint2*)(sg.dst + i) = u;
    }
}

// ---------------------------------------------------------------------------
// LayerNorm over C=256 -> bf16. One wave per token, 4 tokens per block.
// ---------------------------------------------------------------------------
__global__ __launch_bounds__(256) void ln_kernel(const float* __restrict__ X,
                                                 const float* __restrict__ w,
                                                 const float* __restrict__ b,
                                                 ushort_t* __restrict__ Y) {
    int wave = threadIdx.x >> 6, lane = threadIdx.x & 63;
    int t = blockIdx.x * 4 + wave;
    float4 v = *(const float4*)(X + (size_t)t * Cq + lane * 4);
    float s = v.x + v.y + v.z + v.w;
#pragma unroll
    for (int d = 1; d < 64; d <<= 1) s += __shfl_xor(s, d);
    float mean = s * (1.f / 256.f);
    float4 dv = {v.x - mean, v.y - mean, v.z - mean, v.w - mean};
    float q = dv.x * dv.x + dv.y * dv.y + dv.z * dv.z + dv.w * dv.w;
#pragma unroll
    for (int d = 1; d < 64; d <<= 1) q += __shfl_xor(q, d);
    float rs = rsqrtf(q * (1.f / 256.f) + 1e-5f);
    float4 wv = *(const float4*)(w + lane * 4);
    float4 bv = *(const float4*)(b + lane * 4);
    uint2 u;
    u.x = packbf2(dv.x * rs * wv.x + bv.x, dv.y * rs * wv.y + bv.y);
    u.y = packbf2(dv.z * rs * wv.z + bv.z, dv.w * rs * wv.w + bv.w);
    *(uint2*)(Y + (size_t)t * Cq + lane * 4) = u;
}

// ---------------------------------------------------------------------------
// MFMA GEMM with counted-vmcnt double-buffered pipeline (R4 structure —
// measured best for the small projection GEMMs).
// BM=128, BN=64, BK=64; 4 waves, wave w owns rows [w*32, w*32+32).
// LDS: A 2x16KB, B 2x8KB = 48KB. Fragment-ordered chunks: chunk c (0..7)
// holds k=(c&3)*8+(c>>2)*32; wave w stages chunks {w, w+4}.
// Per iter t (cur=t&1): ds_read 12 frags(cur) -> lgkm(0) -> barrier ->
// STAGE(cur, t+2) -> 16 MFMA -> vmcnt(6) [waits only tile t+1] -> barrier.
// MFMA operands swapped (C^T): thread holds 4 consecutive n-values.
// OMODE 0: fp32 out (+bias/residual); OMODE 1: qkv -> bf16 head-major
//          (Q scaled by rsqrt(32)*log2e, V transposed [bh][32][1024]);
// OMODE 2: bf16 out; OMODE 3: fused off/aw (ng<64 -> OffB w/ bias, else AwB
//          w/ R-as-bias; AwB = OutP + BN*64).
// ---------------------------------------------------------------------------
template <int OMODE, bool GELU_, bool RESID, int KT>
__global__ __launch_bounds__(256) void mgemm(const ushort_t* __restrict__ A,
                                             const ushort_t* __restrict__ W,
                                             const float* __restrict__ bias,
                                             const float* __restrict__ R,
                                             void* __restrict__ OutP,
                                             int M, int Nn) {
    __shared__ __align__(16) ushort_t Al[2][8192];
    __shared__ __align__(16) ushort_t Bl[2][4096];
    int m0 = blockIdx.x * 128, n0 = blockIdx.y * 64;
    int tid = threadIdx.x;
    int w = tid >> 6, lane = tid & 63;
    int l15 = lane & 15, quad = lane >> 4;

    f32x4 acc[2][4];
#pragma unroll
    for (int i = 0; i < 2; i++)
#pragma unroll
        for (int j = 0; j < 4; j++) acc[i][j] = (f32x4){0.f, 0.f, 0.f, 0.f};

    const ushort_t* gA0 = A + (size_t)(m0 + lane) * KT + w * 8;
    const ushort_t* gA1 = gA0 + (size_t)64 * KT;
    const ushort_t* gB0 = W + (size_t)(n0 + lane) * KT + w * 8;

    auto STAGE = [&](int buf, int t) {
        const int k0 = t * 64;
        gload16(gA0 + k0,      &Al[buf][w * 1024]);
        gload16(gA1 + k0,      &Al[buf][w * 1024 + 512]);
        gload16(gA0 + k0 + 32, &Al[buf][(w + 4) * 1024]);
        gload16(gA1 + k0 + 32, &Al[buf][(w + 4) * 1024 + 512]);
        gload16(gB0 + k0,      &Bl[buf][w * 512]);
        gload16(gB0 + k0 + 32, &Bl[buf][(w + 4) * 512]);
    };

    constexpr int NT = KT / 64;
    STAGE(0, 0);
    STAGE(1, 1);
    asm volatile("s_waitcnt vmcnt(6)" ::: "memory");   // tile 0 landed
    __builtin_amdgcn_s_barrier();

#pragma unroll
    for (int t = 0; t < NT; t++) {
        const int cur = t & 1;
        bf16x8 aF[2][2], bF[2][4];
#pragma unroll
        for (int ks = 0; ks < 2; ks++) {
#pragma unroll
            for (int i = 0; i < 2; i++)
                aF[ks][i] = *(const bf16x8*)&Al[cur][(ks * 4 + quad) * 1024 + (w * 32 + i * 16 + l15) * 8];
#pragma unroll
            for (int j = 0; j < 4; j++)
                bF[ks][j] = *(const bf16x8*)&Bl[cur][(ks * 4 + quad) * 512 + (j * 16 + l15) * 8];
        }
        asm volatile("s_waitcnt lgkmcnt(0)" ::: "memory");
        __builtin_amdgcn_sched_barrier(0);
        __builtin_amdgcn_s_barrier();        // all waves done reading cur
        if (t + 2 < NT) STAGE(cur, t + 2);

        __builtin_amdgcn_s_setprio(1);
#pragma unroll
        for (int ks = 0; ks < 2; ks++)
#pragma unroll
            for (int i = 0; i < 2; i++)
#pragma unroll
                for (int j = 0; j < 4; j++)
                    acc[i][j] = __builtin_amdgcn_mfma_f32_16x16x32_bf16(bF[ks][j], aF[ks][i], acc[i][j], 0, 0, 0);
        __builtin_amdgcn_s_setprio(0);

        if (t + 2 < NT) {
            asm volatile("s_waitcnt vmcnt(6)" ::: "memory");
        } else if (t + 1 < NT) {
            asm volatile("s_waitcnt vmcnt(0)" ::: "memory");
        }
        if (t + 1 < NT) __builtin_amdgcn_s_barrier();
    }

#pragma unroll
    for (int i = 0; i < 2; i++) {
        int mg = m0 + w * 32 + i * 16 + l15;
#pragma unroll
        for (int j = 0; j < 4; j++) {
            int ng = n0 + j * 16 + quad * 4;
            f32x4 rv = acc[i][j];
            if constexpr (OMODE == 1) {
                int which = ng >> 8;
                int h = (ng >> 5) & 7;
                int d = ng & 31;
                int bb = mg >> 10, nn = mg & 1023;
                ushort_t* qb = (ushort_t*)OutP;
                if (which == 2) {          // V transposed: [bh][d][n]
                    size_t dst = 2 * (size_t)BNq * Cq +
                                 ((size_t)(bb * 8 + h) * 32 + d) * 1024 + nn;
#pragma unroll
                    for (int r = 0; r < 4; r++)
                        qb[dst + (size_t)r * 1024] = (ushort_t)f2bf(rv[r]);
                } else {
                    if (which == 0) {
                        const float sc = 0.17677669529663687f * 1.4426950408889634f;
                        rv[0] *= sc; rv[1] *= sc; rv[2] *= sc; rv[3] *= sc;
                    }
                    size_t dst = (size_t)which * ((size_t)BNq * Cq) +
                                 ((size_t)(bb * 8 + h) * 1024 + nn) * 32 + d;
                    uint2 pk;
                    pk.x = packbf2(rv[0], rv[1]);
                    pk.y = packbf2(rv[2], rv[3]);
                    *(uint2*)(qb + dst) = pk;
                }
            } else if constexpr (OMODE == 3) {
                if (ng >= 96) continue;
                if (ng < 64) {
                    float4 bv = *(const float4*)(bias + ng);
                    rv[0] += bv.x; rv[1] += bv.y; rv[2] += bv.z; rv[3] += bv.w;
                    *(float4*)((float*)OutP + (size_t)mg * 64 + ng) =
                        make_float4(rv[0], rv[1], rv[2], rv[3]);
                } else {
                    float4 bv = *(const float4*)(R + (ng - 64));
                    rv[0] += bv.x; rv[1] += bv.y; rv[2] += bv.z; rv[3] += bv.w;
                    *(float4*)((float*)OutP + (size_t)BNq * 64 + (size_t)mg * 32 + (ng - 64)) =
                        make_float4(rv[0], rv[1], rv[2], rv[3]);
                }
            } else {
                if (bias) {
                    float4 bv = *(const float4*)(bias + ng);
                    rv[0] += bv.x; rv[1] += bv.y; rv[2] += bv.z; rv[3] += bv.w;
                }
                if (GELU_) {
#pragma unroll
                    for (int r = 0; r < 4; r++) rv[r] = gelu_t(rv[r]);
                }
                if constexpr (OMODE == 2) {
                    uint2 pk;
                    pk.x = packbf2(rv[0], rv[1]);
                    pk.y = packbf2(rv[2], rv[3]);
                    *(uint2*)((ushort_t*)OutP + (size_t)mg * Nn + ng) = pk;
                } else {
                    if (RESID) {
                        float4 rr = *(const float4*)(R + (size_t)mg * Nn + ng);
                        rv[0] += rr.x; rv[1] += rr.y; rv[2] += rr.z; rv[3] += rr.w;
                    }
                    *(float4*)((float*)OutP + (size_t)mg * Nn + ng) =
                        make_float4(rv[0], rv[1], rv[2], rv[3]);
                }
            }
        }
    }
}

// ---------------------------------------------------------------------------
// Fused MLP v3: out = X + gelu(Y @ W1^T + b1) @ W2^T + b2, H never leaves LDS.
// N-SPLIT for true 2 blocks/CU: grid 512; block bid computes m-rows
// [(bid>>1)*64, +64) x n-half [ (bid&1)*128, +128 ). GEMM1 (H) is duplicated
// across the pair (+50% MLP flops, ~3us MFMA) but now TWO blocks co-reside
// per CU (LDS 60KB = W1 32 + W2 16 + H 8 + b1 4) and their phases overlap —
// the mechanism R10 proved was missing (capacity 2/CU but grid supplied 1).
// Counted-vmcnt ledger (SW1=8 loads, SW2=4 loads; traced steady state:
// entering chunk ch only SW2(ch)[4] outstanding):
//   GEMM1(W1l,aF) -> bias+gelu -> H ds_write -> lgkm(0) -> B1 [W1l free,
//   H visible] -> SW1(ch+1)[8] -> vmcnt(8) [drains SW2(ch)] -> B2 [W2 ch
//   visible] -> GEMM2 (Hl x W2l -> acc2) -> lgkm(0) -> B3 [W2l+H free] ->
//   SW2(ch+1)[4] -> vmcnt(4) [drains SW1(ch+1), covered by GEMM2] -> B4.
// Tail ch=15: vmcnt(0) at B2, no SW2/B4. Epilogue adds b2 + X residual.
// Layouts (fragment-ordered 8-k chunks, chunk c holds k=(c&3)*8+(c>>2)*32):
//   W1l: [kc 0..31][row h 0..63][8]    addr kc*512+row*8
//   W2l: [kc2 0..7][row nloc 0..127][8] addr kc2*1024+row*8
//   Hl : [kh 0..7][row m 0..63][8]     addr kh*512+row*8
// ---------------------------------------------------------------------------
__global__ __launch_bounds__(256) void mlp_fused(const ushort_t* __restrict__ Y,
                                                 const ushort_t* __restrict__ W1,
                                                 const float* __restrict__ b1,
                                                 const ushort_t* __restrict__ W2,
                                                 const float* __restrict__ b2,
                                                 const float* __restrict__ Xr,
                                                 float* __restrict__ out) {
    __shared__ __align__(16) ushort_t W1l[16384];      // 32 KB
    __shared__ __align__(16) ushort_t W2l[8192];       // 16 KB (n-half)
    __shared__ __align__(16) ushort_t Hl[4096];        // 8 KB
    __shared__ __align__(16) float b1l[1024];          // 4 KB
    int bid = blockIdx.x;
    int m0 = (bid >> 1) * 64;
    int nh = bid & 1;                  // output n-half: [nh*128, nh*128+128)
    int tid = threadIdx.x;
    int w = tid >> 6, lane = tid & 63;
    int l15 = lane & 15, quad = lane >> 4;

    // A rows in registers: row = m0 + w*16 + l15, k = ks*32 + quad*8
    bf16x8 aF[8];
    {
        const ushort_t* ga = Y + (size_t)(m0 + w * 16 + l15) * 256 + quad * 8;
#pragma unroll
        for (int ks = 0; ks < 8; ks++) aF[ks] = *(const bf16x8*)(ga + ks * 32);
    }

    // stage W1 chunk ch (64 h-rows x 256 k): wave w stages kc = w + 4j  [8 loads]
    auto SW1 = [&](int ch) {
        const ushort_t* g = W1 + (size_t)(ch * 64 + lane) * 256 + w * 8;
#pragma unroll
        for (int j = 0; j < 8; j++)
            gload16(g + j * 32, &W1l[(w + 4 * j) * 512]);
    };
    // stage W2 chunk ch, n-half nh (128 n-rows x 64 hid): kc2 = {w, w+4},
    // 2 row-groups of 64  [4 loads]
    auto SW2 = [&](int ch) {
#pragma unroll
        for (int jj = 0; jj < 4; jj++) {
            const int kc2 = (jj & 1) * 4 + w;
            const int rj = jj >> 1;
            const ushort_t* g = W2 + (size_t)(nh * 128 + rj * 64 + lane) * 1024 +
                                ch * 64 + (kc2 & 3) * 8 + (kc2 >> 2) * 32;
            gload16(g, &W2l[kc2 * 1024 + rj * 512]);
        }
    };

    f32x4 acc2[4][2];
#pragma unroll
    for (int i = 0; i < 4; i++)
#pragma unroll
        for (int j = 0; j < 2; j++) acc2[i][j] = (f32x4){0.f, 0.f, 0.f, 0.f};

    // prologue: stage chunk 0 of both weights + bias, full drain once.
    SW1(0);
    SW2(0);
    gload16(b1 + w * 256 + lane * 4, &b1l[w * 256]);   // bias -> LDS
    asm volatile("s_waitcnt vmcnt(0)" ::: "memory");
    __builtin_amdgcn_s_barrier();

    for (int ch = 0; ch < 16; ch++) {
        // ---- GEMM1: H(64x64) = A(64x256) @ W1[ch]^T ----
        f32x4 acc1[4];
#pragma unroll
        for (int j = 0; j < 4; j++) acc1[j] = (f32x4){0.f, 0.f, 0.f, 0.f};
#pragma unroll
        for (int ks = 0; ks < 8; ks++) {
            bf16x8 bF[4];
#pragma unroll
            for (int j = 0; j < 4; j++)
                bF[j] = *(const bf16x8*)&W1l[(ks * 4 + quad) * 512 + (j * 16 + l15) * 8];
#pragma unroll
            for (int j = 0; j < 4; j++)
                acc1[j] = __builtin_amdgcn_mfma_f32_16x16x32_bf16(bF[j], aF[ks], acc1[j], 0, 0, 0);
        }
        // ---- bias + gelu -> H LDS (GEMM2-fragment order) ----
#pragma unroll
        for (int j = 0; j < 4; j++) {
            float4 b1v = *(const float4*)&b1l[ch * 64 + j * 16 + quad * 4];
            f32x4 rv = acc1[j];
            rv[0] = gelu_t(rv[0] + b1v.x);
            rv[1] = gelu_t(rv[1] + b1v.y);
            rv[2] = gelu_t(rv[2] + b1v.z);
            rv[3] = gelu_t(rv[3] + b1v.w);
            int h = j * 16 + quad * 4;
            uint2 pk;
            pk.x = cvtpk_bf16(rv[0], rv[1]);
            pk.y = cvtpk_bf16(rv[2], rv[3]);
            *(uint2*)&Hl[((h >> 3) * 64 + (w * 16 + l15)) * 8 + (h & 7)] = pk;
        }
        asm volatile("s_waitcnt lgkmcnt(0)" ::: "memory");  // W1 reads + H writes done
        __builtin_amdgcn_sched_barrier(0);
        __builtin_amdgcn_s_barrier();          // B1: W1l free; H visible
        if (ch + 1 < 16) {
            SW1(ch + 1);                        // 8 loads into W1l
            asm volatile("s_waitcnt vmcnt(8)" ::: "memory"); // SW2(ch) landed
        } else {
            asm volatile("s_waitcnt vmcnt(0)" ::: "memory");
        }
        __builtin_amdgcn_s_barrier();          // B2: W2[ch] visible to all

        // ---- GEMM2: acc2 += H(64x64) @ W2[ch]^T (wave w owns n-cols
        //      [nh*128 + w*32, +32)) ----
        __builtin_amdgcn_s_setprio(1);
#pragma unroll
        for (int ks2 = 0; ks2 < 2; ks2++) {
            bf16x8 a2[4], b2f[2];
#pragma unroll
            for (int i = 0; i < 4; i++)
                a2[i] = *(const bf16x8*)&Hl[(ks2 * 4 + quad) * 512 + (i * 16 + l15) * 8];
#pragma unroll
            for (int j = 0; j < 2; j++)
                b2f[j] = *(const bf16x8*)&W2l[(ks2 * 4 + quad) * 1024 + (w * 32 + j * 16 + l15) * 8];
#pragma unroll
            for (int i = 0; i < 4; i++)
#pragma unroll
                for (int j = 0; j < 2; j++)
                    acc2[i][j] = __builtin_amdgcn_mfma_f32_16x16x32_bf16(b2f[j], a2[i], acc2[i][j], 0, 0, 0);
        }
        __builtin_amdgcn_s_setprio(0);
        asm volatile("s_waitcnt lgkmcnt(0)" ::: "memory");  // W2/H reads retired
        __builtin_amdgcn_sched_barrier(0);
        __builtin_amdgcn_s_barrier();          // B3: W2l + Hl free
        if (ch + 1 < 16) {
            SW2(ch + 1);                        // 4 loads into W2l
            asm volatile("s_waitcnt vmcnt(4)" ::: "memory"); // SW1(ch+1) landed
            __builtin_amdgcn_s_barrier();      // B4: W1[ch+1] visible to all
        }
    }

    // ---- epilogue: out = acc2 + b2 + X ----
#pragma unroll
    for (int i = 0; i < 4; i++) {
        int mg = m0 + i * 16 + l15;
#pragma unroll
        for (int j = 0; j < 2; j++) {
            int ng = nh * 128 + w * 32 + j * 16 + quad * 4;
            f32x4 rv = acc2[i][j];
            float4 bv = *(const float4*)(b2 + ng);
            float4 rr = *(const float4*)(Xr + (size_t)mg * 256 + ng);
            rv[0] += bv.x + rr.x; rv[1] += bv.y + rr.y;
            rv[2] += bv.z + rr.z; rv[3] += bv.w + rr.w;
            *(float4*)(out + (size_t)mg * 256 + ng) =
                make_float4(rv[0], rv[1], rv[2], rv[3]);
        }
    }
}

// ---------------------------------------------------------------------------
// MFMA flash attention v2 (unchanged from R4).
// ---------------------------------------------------------------------------
__global__ __launch_bounds__(256, 4) void attn_mfma(const ushort_t* __restrict__ Qb,
                                                    const ushort_t* __restrict__ Kb,
                                                    const ushort_t* __restrict__ Vtg,
                                                    ushort_t* __restrict__ o) {
    int bh = blockIdx.x;
    int b = bh >> 3, h = bh & 7;
    int q0 = blockIdx.y * 128;
    int tid = threadIdx.x;
    int wave = tid >> 6, lane = tid & 63;
    int l15 = lane & 15, quad = lane >> 4;

    __shared__ __align__(16) ushort_t Ks[2][64][40];     // [buf][key][d]
    __shared__ __align__(16) ushort_t Vs[2][32][88];     // [buf][d][key]
    __shared__ __align__(16) ushort_t Ps[4][32][72];     // per wave [q][key]

    const size_t hb = (size_t)bh * 32768;

    bf16x8 qfrag[2];
#pragma unroll
    for (int g = 0; g < 2; g++)
        qfrag[g] = *(const bf16x8*)(Qb + hb + (size_t)(q0 + wave * 32 + g * 16 + l15) * 32 + quad * 8);

    f32x4 oa[2][2];
#pragma unroll
    for (int g = 0; g < 2; g++)
#pragma unroll
        for (int t = 0; t < 2; t++) oa[g][t] = (f32x4){0.f, 0.f, 0.f, 0.f};
    f32x4 ls[2];
    ls[0] = (f32x4){0.f, 0.f, 0.f, 0.f};
    ls[1] = (f32x4){0.f, 0.f, 0.f, 0.f};

    bf16x8 ones;
#pragma unroll
    for (int i = 0; i < 8; i++) ones[i] = (short)0x3F80;   // bf16 1.0

    int krow = tid >> 2, kch = tid & 3;
    int vrow = tid >> 3, vch = tid & 7;
    const ushort_t* kgp = Kb + hb + (size_t)krow * 32 + kch * 8;
    const ushort_t* vgp = Vtg + hb + (size_t)vrow * 1024 + vch * 8;

    // prefetch tile 0 into registers
    bf16x8 kreg = *(const bf16x8*)kgp;
    bf16x8 vreg = *(const bf16x8*)vgp;

#pragma unroll 2
    for (int kt = 0; kt < 16; kt++) {
        const int cur = kt & 1;
        *(bf16x8*)&Ks[cur][krow][kch * 8] = kreg;
        *(bf16x8*)&Vs[cur][vrow][vch * 8] = vreg;
        __syncthreads();
        if (kt < 15) {
            kreg = *(const bf16x8*)(kgp + (kt + 1) * 2048);
            vreg = *(const bf16x8*)(vgp + (kt + 1) * 64);
        }

        bf16x8 kf[4];
#pragma unroll
        for (int kg = 0; kg < 4; kg++)
            kf[kg] = *(const bf16x8*)&Ks[cur][kg * 16 + l15][quad * 8];

        const f32x4 z = {0.f, 0.f, 0.f, 0.f};
#pragma unroll
        for (int g = 0; g < 2; g++) {
#pragma unroll
            for (int kg = 0; kg < 4; kg++) {
                f32x4 st = __builtin_amdgcn_mfma_f32_16x16x32_bf16(kf[kg], qfrag[g], z, 0, 0, 0);
                float e0 = __builtin_amdgcn_exp2f(st[0]);
                float e1 = __builtin_amdgcn_exp2f(st[1]);
                float e2 = __builtin_amdgcn_exp2f(st[2]);
                float e3 = __builtin_amdgcn_exp2f(st[3]);
                uint2 pk;
                pk.x = cvtpk_bf16(e0, e1);
                pk.y = cvtpk_bf16(e2, e3);
                *(uint2*)&Ps[wave][g * 16 + l15][kg * 16 + quad * 4] = pk;
            }
        }

        __builtin_amdgcn_s_setprio(1);
#pragma unroll
        for (int c = 0; c < 2; c++) {
            bf16x8 vb0 = *(const bf16x8*)&Vs[cur][l15][c * 32 + quad * 8];
            bf16x8 vb1 = *(const bf16x8*)&Vs[cur][16 + l15][c * 32 + quad * 8];
#pragma unroll
            for (int g = 0; g < 2; g++) {
                bf16x8 pa = *(const bf16x8*)&Ps[wave][g * 16 + l15][c * 32 + quad * 8];
                oa[g][0] = __builtin_amdgcn_mfma_f32_16x16x32_bf16(pa, vb0, oa[g][0], 0, 0, 0);
                oa[g][1] = __builtin_amdgcn_mfma_f32_16x16x32_bf16(pa, vb1, oa[g][1], 0, 0, 0);
                ls[g]    = __builtin_amdgcn_mfma_f32_16x16x32_bf16(pa, ones, ls[g], 0, 0, 0);
            }
        }
        __builtin_amdgcn_s_setprio(0);
    }

#pragma unroll
    for (int g = 0; g < 2; g++) {
#pragma unroll
        for (int r = 0; r < 4; r++) {
            float inv = 1.f / ls[g][r];
            int q = q0 + wave * 32 + g * 16 + quad * 4 + r;
            ushort_t* orow = o + ((size_t)(b * 1024 + q)) * 256 + h * 32;
            orow[l15] = (ushort_t)f2bf(oa[g][0][r] * inv);
            orow[l15 + 16] = (ushort_t)f2bf(oa[g][1][r] * inv);
        }
    }
}

// ---------------------------------------------------------------------------
// Deformable gather -> bf16. One block per token, thread = (h=tid>>5, d=tid&31).
// ---------------------------------------------------------------------------
__global__ __launch_bounds__(256) void deform_kernel(const float* __restrict__ ref,
                                                     const float* __restrict__ off,
                                                     const float* __restrict__ awl,
                                                     const float* __restrict__ v,
                                                     ushort_t* __restrict__ out) {
    int t = blockIdx.x;
    int b = t >> 10;
    int tid = threadIdx.x;
    int h = tid >> 5, d = tid & 31;

    float rx = ref[(size_t)t * 2 + 0];
    float ry = ref[(size_t)t * 2 + 1];
    const float* offr = off + (size_t)t * 64 + h * 8;
    const float* awr = awl + (size_t)t * 32 + h * 4;

    float L0 = awr[0], L1 = awr[1], L2 = awr[2], L3 = awr[3];
    float mm = fmaxf(fmaxf(L0, L1), fmaxf(L2, L3));
    float e0 = __expf(L0 - mm), e1 = __expf(L1 - mm), e2 = __expf(L2 - mm), e3 = __expf(L3 - mm);
    float inv = 1.f / (e0 + e1 + e2 + e3);
    float aw[4] = {e0 * inv, e1 * inv, e2 * inv, e3 * inv};

    const float* vb = v + (size_t)b * Nq * Cq + h * 32 + d;

    float s = 0.f;
#pragma unroll
    for (int p = 0; p < 4; p++) {
        float gx = rx * 32.f + offr[p * 2 + 0] - 0.5f;
        float gy = ry * 32.f + offr[p * 2 + 1] - 0.5f;
        float x0f = floorf(gx), y0f = floorf(gy);
        float lx = gx - x0f, ly = gy - y0f;
        int x0 = (int)x0f, y0 = (int)y0f;
        auto g = [&](int xi, int yi) -> float {
            if (xi < 0 || xi > 31 || yi < 0 || yi > 31) return 0.f;
            return vb[(size_t)(yi * 32 + xi) * Cq];
        };
        float sp = g(x0, y0) * (1.f - lx) * (1.f - ly)
                 + g(x0 + 1, y0) * lx * (1.f - ly)
                 + g(x0, y0 + 1) * (1.f - lx) * ly
                 + g(x0 + 1, y0 + 1) * lx * ly;
        s += aw[p] * sp;
    }
    out[(size_t)t * Cq + h * 32 + d] = (ushort_t)f2bf(s);
}

// ---------------------------------------------------------------------------
// Launch
// ---------------------------------------------------------------------------
extern "C" void kernel_launch(void* const* d_in, const int* in_sizes, int n_in,
                              void* d_out, int out_size, void* d_ws, size_t ws_size,
                              hipStream_t stream) {
    const size_t S = (size_t)BNq * Cq;  // 4,194,304
    float* ws = (float*)d_ws;
    float* X = ws;                                  // [0, S) residual fp32
    ushort_t* Ybf = (ushort_t*)(ws + S);            // [S, 1.5S)
    ushort_t* Wbf = (ushort_t*)(ws + S + S / 2);    // [1.5S, 2S)

    ushort_t* Wqkv   = Wbf;
    ushort_t* Wproj  = Wbf + 196608;
    ushort_t* Woff   = Wbf + 262144;   // off(64 rows) + aw(32 rows) contiguous
    ushort_t* Waw    = Wbf + 278528;
    ushort_t* Wvproj = Wbf + 286720;
    ushort_t* Woproj = Wbf + 352256;
    ushort_t* Wfc1   = Wbf + 417792;
    ushort_t* Wfc2   = Wbf + 679936;

    ushort_t* QKVbf = (ushort_t*)(ws + 2 * S);              // Q,K,V^T: [2S, 3.5S)
    ushort_t* O1bf  = (ushort_t*)(ws + 2 * S + 3 * S / 2);  // [3.5S, 4S)
    float* Vb   = ws + 2 * S + S / 2;                       // [2.5S, 3.5S)
    float* OffB = ws + 2 * S + 3 * S / 2;                   // [3.5S, 3.75S)
    float* AwB  = OffB + (size_t)BNq * 64;                  // [3.75S, 3.875S)
    ushort_t* Sbbf = (ushort_t*)(AwB + (size_t)BNq * 32);   // [3.875S, 4.375S)
    ushort_t* Valbf = (ushort_t*)(ws + 9 * S / 2);          // [4.5S, 5S)

    auto fp = [&](int i) { return (const float*)d_in[i]; };
    const float* x_in = fp(0);

    // ---- all fp32->bf16 casts in one dispatch ----
    CastArgs ca;
    ca.s[0] = {fp(9),  Wqkv,   192, 196608};
    ca.s[1] = {fp(10), Wproj,  64,  65536};
    ca.s[2] = {fp(12), Woff,   16,  16384};
    ca.s[3] = {fp(14), Waw,    8,   8192};
    ca.s[4] = {fp(16), Wvproj, 64,  65536};
    ca.s[5] = {fp(18), Woproj, 64,  65536};
    ca.s[6] = {fp(20), Wfc1,   256, 262144};
    ca.s[7] = {fp(22), Wfc2,   256, 262144};
    ca.s[8] = {fp(2),  Valbf,  4096, (int)S};
    castm<<<5016, 256, 0, stream>>>(ca);

    // ---- stage 1: self-attention ----
    ln_kernel<<<BNq / 4, 256, 0, stream>>>(x_in, fp(3), fp(4), Ybf);
    mgemm<1, false, false, 256><<<dim3(128, 12), 256, 0, stream>>>(
        Ybf, Wqkv, nullptr, nullptr, QKVbf, BNq, 768);
    attn_mfma<<<dim3(128, 8), 256, 0, stream>>>(
        QKVbf, QKVbf + S, QKVbf + 2 * S, O1bf);
    mgemm<0, false, true, 256><<<dim3(128, 4), 256, 0, stream>>>(
        O1bf, Wproj, fp(11), x_in, X, BNq, 256);

    // ---- stage 2: deformable attention ----
    ln_kernel<<<BNq / 4, 256, 0, stream>>>(X, fp(5), fp(6), Ybf);
    mgemm<0, false, false, 256><<<dim3(128, 4), 256, 0, stream>>>(
        Valbf, Wvproj, fp(17), nullptr, Vb, BNq, 256);
    mgemm<3, false, false, 256><<<dim3(128, 2), 256, 0, stream>>>(
        Ybf, Woff, fp(13), fp(15), OffB, BNq, 96);
    deform_kernel<<<BNq, 256, 0, stream>>>(fp(1), OffB, AwB, Vb, Sbbf);
    mgemm<0, false, true, 256><<<dim3(128, 4), 256, 0, stream>>>(
        Sbbf, Woproj, fp(19), X, X, BNq, 256);

    // ---- stage 3: MLP (fused fc1+gelu+fc2+residual; H stays in LDS) ----
    ln_kernel<<<BNq / 4, 256, 0, stream>>>(X, fp(7), fp(8), Ybf);
    mlp_fused<<<BNq / 32, 256, 0, stream>>>(
        Ybf, Wfc1, fp(21), Wfc2, fp(23), X, (float*)d_out);
}

// Round 12
// 315.774 us; speedup vs baseline: 1.0697x; 1.0259x over previous
//
#include <hip/hip_runtime.h>
#include <hip/hip_bf16.h>

// Problem constants
#define Bq   16
#define Nq   1024
#define Cq   256
#define NHq  8
#define DHq  32
#define HIDq 1024
#define BNq  (Bq * Nq)   // 16384 tokens

typedef float f32x4 __attribute__((ext_vector_type(4)));
typedef short bf16x8 __attribute__((ext_vector_type(8)));
typedef unsigned int u32x4 __attribute__((ext_vector_type(4)));
typedef unsigned short ushort_t;

__device__ __forceinline__ unsigned int f2bf(float f) {   // RNE
    unsigned int u = __builtin_bit_cast(unsigned int, f);
    u = (u + 0x7fffu + ((u >> 16) & 1u)) >> 16;
    return u & 0xffffu;
}
// pack two floats -> two bf16 (round-half-up) in one dword via v_perm
__device__ __forceinline__ unsigned int packbf2(float a, float b) {
    unsigned int ua = __builtin_bit_cast(unsigned int, a) + 0x8000u;
    unsigned int ub = __builtin_bit_cast(unsigned int, b) + 0x8000u;
    return __builtin_amdgcn_perm(ub, ua, 0x07060302);
}
// single-instruction packed f32x2 -> bf16x2 (RNE); lo -> low half
__device__ __forceinline__ unsigned int cvtpk_bf16(float lo, float hi) {
    unsigned int r;
    asm("v_cvt_pk_bf16_f32 %0, %1, %2" : "=v"(r) : "v"(lo), "v"(hi));
    return r;
}
// branch-free tanh-approx GELU
__device__ __forceinline__ float gelu_t(float x) {
    float y = x * (0.7978845608028654f + 0.035677408136300125f * x * x);
    float e = __builtin_amdgcn_exp2f(y * 2.8853900817779268f);
    return x - x / (1.f + e);
}

typedef __attribute__((address_space(1))) const unsigned int* gas_u32;
typedef __attribute__((address_space(3))) unsigned int* las_u32;
__device__ __forceinline__ void gload16(const void* g, void* l) {
    __builtin_amdgcn_global_load_lds((gas_u32)g, (las_u32)l, 16, 0, 0);
}

// ---------------------------------------------------------------------------
// Fused fp32 -> bf16 casts: 9 segments in one dispatch.
// ---------------------------------------------------------------------------
struct CastSeg { const float* src; ushort_t* dst; int nblk; int n; };
struct CastArgs { CastSeg s[9]; };

__global__ __launch_bounds__(256) void castm(CastArgs a) {
    int bid = blockIdx.x;
    int seg = 0, acc = 0;
    for (seg = 0; seg < 9; seg++) {
        if (bid < acc + a.s[seg].nblk) break;
        acc += a.s[seg].nblk;
    }
    const CastSeg sg = a.s[seg];
    int i = (bid - acc) * 1024 + threadIdx.x * 4;
    if (i < sg.n) {
        float4 v = *(const float4*)(sg.src + i);
        uint2 u;
        u.x = packbf2(v.x, v.y);
        u.y = packbf2(v.z, v.w);
        *(uint2*)(sg.dst + i) = u;
    }
}

// ---------------------------------------------------------------------------
// LayerNorm over C=256 -> bf16. One wave per token, 4 tokens per block.
// ---------------------------------------------------------------------------
__global__ __launch_bounds__(256) void ln_kernel(const float* __restrict__ X,
                                                 const float* __restrict__ w,
                                                 const float* __restrict__ b,
                                                 ushort_t* __restrict__ Y) {
    int wave = threadIdx.x >> 6, lane = threadIdx.x & 63;
    int t = blockIdx.x * 4 + wave;
    float4 v = *(const float4*)(X + (size_t)t * Cq + lane * 4);
    float s = v.x + v.y + v.z + v.w;
#pragma unroll
    for (int d = 1; d < 64; d <<= 1) s += __shfl_xor(s, d);
    float mean = s * (1.f / 256.f);
    float4 dv = {v.x - mean, v.y - mean, v.z - mean, v.w - mean};
    float q = dv.x * dv.x + dv.y * dv.y + dv.z * dv.z + dv.w * dv.w;
#pragma unroll
    for (int d = 1; d < 64; d <<= 1) q += __shfl_xor(q, d);
    float rs = rsqrtf(q * (1.f / 256.f) + 1e-5f);
    float4 wv = *(const float4*)(w + lane * 4);
    float4 bv = *(const float4*)(b + lane * 4);
    uint2 u;
    u.x = packbf2(dv.x * rs * wv.x + bv.x, dv.y * rs * wv.y + bv.y);
    u.y = packbf2(dv.z * rs * wv.z + bv.z, dv.w * rs * wv.w + bv.w);
    *(uint2*)(Y + (size_t)t * Cq + lane * 4) = u;
}

// ---------------------------------------------------------------------------
// MFMA GEMM with counted-vmcnt double-buffered pipeline (R4 structure —
// measured best for the small projection GEMMs).
// BM=128, BN=64, BK=64; 4 waves, wave w owns rows [w*32, w*32+32).
// LDS: A 2x16KB, B 2x8KB = 48KB. Fragment-ordered chunks: chunk c (0..7)
// holds k=(c&3)*8+(c>>2)*32; wave w stages chunks {w, w+4}.
// Per iter t (cur=t&1): ds_read 12 frags(cur) -> lgkm(0) -> barrier ->
// STAGE(cur, t+2) -> 16 MFMA -> vmcnt(6) [waits only tile t+1] -> barrier.
// MFMA operands swapped (C^T): thread holds 4 consecutive n-values.
// OMODE 0: fp32 out (+bias/residual); OMODE 1: qkv -> bf16 head-major
//          (Q scaled by rsqrt(32)*log2e, V transposed [bh][32][1024]);
// OMODE 2: bf16 out; OMODE 3: fused off/aw (ng<64 -> OffB w/ bias, else AwB
//          w/ R-as-bias; AwB = OutP + BN*64).
// ---------------------------------------------------------------------------
template <int OMODE, bool GELU_, bool RESID, int KT>
__global__ __launch_bounds__(256) void mgemm(const ushort_t* __restrict__ A,
                                             const ushort_t* __restrict__ W,
                                             const float* __restrict__ bias,
                                             const float* __restrict__ R,
                                             void* __restrict__ OutP,
                                             int M, int Nn) {
    __shared__ __align__(16) ushort_t Al[2][8192];
    __shared__ __align__(16) ushort_t Bl[2][4096];
    int m0 = blockIdx.x * 128, n0 = blockIdx.y * 64;
    int tid = threadIdx.x;
    int w = tid >> 6, lane = tid & 63;
    int l15 = lane & 15, quad = lane >> 4;

    f32x4 acc[2][4];
#pragma unroll
    for (int i = 0; i < 2; i++)
#pragma unroll
        for (int j = 0; j < 4; j++) acc[i][j] = (f32x4){0.f, 0.f, 0.f, 0.f};

    const ushort_t* gA0 = A + (size_t)(m0 + lane) * KT + w * 8;
    const ushort_t* gA1 = gA0 + (size_t)64 * KT;
    const ushort_t* gB0 = W + (size_t)(n0 + lane) * KT + w * 8;

    auto STAGE = [&](int buf, int t) {
        const int k0 = t * 64;
        gload16(gA0 + k0,      &Al[buf][w * 1024]);
        gload16(gA1 + k0,      &Al[buf][w * 1024 + 512]);
        gload16(gA0 + k0 + 32, &Al[buf][(w + 4) * 1024]);
        gload16(gA1 + k0 + 32, &Al[buf][(w + 4) * 1024 + 512]);
        gload16(gB0 + k0,      &Bl[buf][w * 512]);
        gload16(gB0 + k0 + 32, &Bl[buf][(w + 4) * 512]);
    };

    constexpr int NT = KT / 64;
    STAGE(0, 0);
    STAGE(1, 1);
    asm volatile("s_waitcnt vmcnt(6)" ::: "memory");   // tile 0 landed
    __builtin_amdgcn_s_barrier();

#pragma unroll
    for (int t = 0; t < NT; t++) {
        const int cur = t & 1;
        bf16x8 aF[2][2], bF[2][4];
#pragma unroll
        for (int ks = 0; ks < 2; ks++) {
#pragma unroll
            for (int i = 0; i < 2; i++)
                aF[ks][i] = *(const bf16x8*)&Al[cur][(ks * 4 + quad) * 1024 + (w * 32 + i * 16 + l15) * 8];
#pragma unroll
            for (int j = 0; j < 4; j++)
                bF[ks][j] = *(const bf16x8*)&Bl[cur][(ks * 4 + quad) * 512 + (j * 16 + l15) * 8];
        }
        asm volatile("s_waitcnt lgkmcnt(0)" ::: "memory");
        __builtin_amdgcn_sched_barrier(0);
        __builtin_amdgcn_s_barrier();        // all waves done reading cur
        if (t + 2 < NT) STAGE(cur, t + 2);

        __builtin_amdgcn_s_setprio(1);
#pragma unroll
        for (int ks = 0; ks < 2; ks++)
#pragma unroll
            for (int i = 0; i < 2; i++)
#pragma unroll
                for (int j = 0; j < 4; j++)
                    acc[i][j] = __builtin_amdgcn_mfma_f32_16x16x32_bf16(bF[ks][j], aF[ks][i], acc[i][j], 0, 0, 0);
        __builtin_amdgcn_s_setprio(0);

        if (t + 2 < NT) {
            asm volatile("s_waitcnt vmcnt(6)" ::: "memory");
        } else if (t + 1 < NT) {
            asm volatile("s_waitcnt vmcnt(0)" ::: "memory");
        }
        if (t + 1 < NT) __builtin_amdgcn_s_barrier();
    }

#pragma unroll
    for (int i = 0; i < 2; i++) {
        int mg = m0 + w * 32 + i * 16 + l15;
#pragma unroll
        for (int j = 0; j < 4; j++) {
            int ng = n0 + j * 16 + quad * 4;
            f32x4 rv = acc[i][j];
            if constexpr (OMODE == 1) {
                int which = ng >> 8;
                int h = (ng >> 5) & 7;
                int d = ng & 31;
                int bb = mg >> 10, nn = mg & 1023;
                ushort_t* qb = (ushort_t*)OutP;
                if (which == 2) {          // V transposed: [bh][d][n]
                    size_t dst = 2 * (size_t)BNq * Cq +
                                 ((size_t)(bb * 8 + h) * 32 + d) * 1024 + nn;
#pragma unroll
                    for (int r = 0; r < 4; r++)
                        qb[dst + (size_t)r * 1024] = (ushort_t)f2bf(rv[r]);
                } else {
                    if (which == 0) {
                        const float sc = 0.17677669529663687f * 1.4426950408889634f;
                        rv[0] *= sc; rv[1] *= sc; rv[2] *= sc; rv[3] *= sc;
                    }
                    size_t dst = (size_t)which * ((size_t)BNq * Cq) +
                                 ((size_t)(bb * 8 + h) * 1024 + nn) * 32 + d;
                    uint2 pk;
                    pk.x = packbf2(rv[0], rv[1]);
                    pk.y = packbf2(rv[2], rv[3]);
                    *(uint2*)(qb + dst) = pk;
                }
            } else if constexpr (OMODE == 3) {
                if (ng >= 96) continue;
                if (ng < 64) {
                    float4 bv = *(const float4*)(bias + ng);
                    rv[0] += bv.x; rv[1] += bv.y; rv[2] += bv.z; rv[3] += bv.w;
                    *(float4*)((float*)OutP + (size_t)mg * 64 + ng) =
                        make_float4(rv[0], rv[1], rv[2], rv[3]);
                } else {
                    float4 bv = *(const float4*)(R + (ng - 64));
                    rv[0] += bv.x; rv[1] += bv.y; rv[2] += bv.z; rv[3] += bv.w;
                    *(float4*)((float*)OutP + (size_t)BNq * 64 + (size_t)mg * 32 + (ng - 64)) =
                        make_float4(rv[0], rv[1], rv[2], rv[3]);
                }
            } else {
                if (bias) {
                    float4 bv = *(const float4*)(bias + ng);
                    rv[0] += bv.x; rv[1] += bv.y; rv[2] += bv.z; rv[3] += bv.w;
                }
                if (GELU_) {
#pragma unroll
                    for (int r = 0; r < 4; r++) rv[r] = gelu_t(rv[r]);
                }
                if constexpr (OMODE == 2) {
                    uint2 pk;
                    pk.x = packbf2(rv[0], rv[1]);
                    pk.y = packbf2(rv[2], rv[3]);
                    *(uint2*)((ushort_t*)OutP + (size_t)mg * Nn + ng) = pk;
                } else {
                    if (RESID) {
                        float4 rr = *(const float4*)(R + (size_t)mg * Nn + ng);
                        rv[0] += rr.x; rv[1] += rr.y; rv[2] += rr.z; rv[3] += rr.w;
                    }
                    *(float4*)((float*)OutP + (size_t)mg * Nn + ng) =
                        make_float4(rv[0], rv[1], rv[2], rv[3]);
                }
            }
        }
    }
}

// ---------------------------------------------------------------------------
// Fused MLP v4: out = X + gelu(LN3(X) @ W1^T + b1) @ W2^T + b2.
// LN3 FUSED IN-REGISTER (drops the third ln_kernel dispatch + Ybf round
// trip): each block owns complete 64-token rows; a row's 256 channels live
// in 4 lanes (quads) x 16 f32x4 regs, so LN = in-lane reduce + 2 shfl_xor
// hops (16, 32) — exactly ln_kernel's pattern. ln_w/ln_b staged to LDS.
// N-split (R11): grid 512; block bid = m-rows [(bid>>1)*64,+64) x n-half
// [(bid&1)*128,+128). GEMM1 duplicated across the pair; 2 blocks/CU
// co-reside (LDS 62KB) and overlap phases (R11-measured: occupancy 19%,
// absorbs the duplicate flops at flat time).
// Counted-vmcnt ledger unchanged (SW1=8, SW2=4; prologue full drain; loop
// vmcnt(8)/vmcnt(4); tail vmcnt(0)). Phase chain identical to R11.
// Layouts (fragment-ordered 8-k chunks, chunk c holds k=(c&3)*8+(c>>2)*32):
//   W1l: [kc 0..31][row h 0..63][8]    addr kc*512+row*8
//   W2l: [kc2 0..7][row nloc 0..127][8] addr kc2*1024+row*8
//   Hl : [kh 0..7][row m 0..63][8]     addr kh*512+row*8
// ---------------------------------------------------------------------------
__global__ __launch_bounds__(256) void mlp_fused(const float* __restrict__ X,
                                                 const ushort_t* __restrict__ W1,
                                                 const float* __restrict__ b1,
                                                 const ushort_t* __restrict__ W2,
                                                 const float* __restrict__ b2,
                                                 const float* __restrict__ lnw,
                                                 const float* __restrict__ lnb,
                                                 float* __restrict__ out) {
    __shared__ __align__(16) ushort_t W1l[16384];      // 32 KB
    __shared__ __align__(16) ushort_t W2l[8192];       // 16 KB (n-half)
    __shared__ __align__(16) ushort_t Hl[4096];        // 8 KB
    __shared__ __align__(16) float b1l[1024];          // 4 KB
    __shared__ __align__(16) float lnwl[256];          // 1 KB
    __shared__ __align__(16) float lnbl[256];          // 1 KB
    int bid = blockIdx.x;
    int m0 = (bid >> 1) * 64;
    int nh = bid & 1;                  // output n-half: [nh*128, nh*128+128)
    int tid = threadIdx.x;
    int w = tid >> 6, lane = tid & 63;
    int l15 = lane & 15, quad = lane >> 4;

    // stage W1 chunk ch (64 h-rows x 256 k): wave w stages kc = w + 4j  [8 loads]
    auto SW1 = [&](int ch) {
        const ushort_t* g = W1 + (size_t)(ch * 64 + lane) * 256 + w * 8;
#pragma unroll
        for (int j = 0; j < 8; j++)
            gload16(g + j * 32, &W1l[(w + 4 * j) * 512]);
    };
    // stage W2 chunk ch, n-half nh (128 n-rows x 64 hid): kc2 = {w, w+4},
    // 2 row-groups of 64  [4 loads]
    auto SW2 = [&](int ch) {
#pragma unroll
        for (int jj = 0; jj < 4; jj++) {
            const int kc2 = (jj & 1) * 4 + w;
            const int rj = jj >> 1;
            const ushort_t* g = W2 + (size_t)(nh * 128 + rj * 64 + lane) * 1024 +
                                ch * 64 + (kc2 & 3) * 8 + (kc2 >> 2) * 32;
            gload16(g, &W2l[kc2 * 1024 + rj * 512]);
        }
    };

    f32x4 acc2[4][2];
#pragma unroll
    for (int i = 0; i < 4; i++)
#pragma unroll
        for (int j = 0; j < 2; j++) acc2[i][j] = (f32x4){0.f, 0.f, 0.f, 0.f};

    // prologue: stage weights chunk 0, bias, ln params; load X rows to regs;
    // one full drain.
    SW1(0);
    SW2(0);
    gload16(b1 + w * 256 + lane * 4, &b1l[w * 256]);   // bias -> LDS
    if (w == 0) gload16(lnw + lane * 4, &lnwl[0]);     // ln weight -> LDS
    if (w == 1) gload16(lnb + lane * 4, &lnbl[0]);     // ln bias -> LDS

    // LN3 input: row = m0 + w*16 + l15, channels k = ks*32 + quad*8 + j
    float4 xv[16];
    {
        const float* gx = X + (size_t)(m0 + w * 16 + l15) * 256 + quad * 8;
#pragma unroll
        for (int ks = 0; ks < 8; ks++) {
            xv[2 * ks]     = *(const float4*)(gx + ks * 32);
            xv[2 * ks + 1] = *(const float4*)(gx + ks * 32 + 4);
        }
    }
    asm volatile("s_waitcnt vmcnt(0)" ::: "memory");
    __builtin_amdgcn_s_barrier();

    // ---- LN3 in-register: quads of a row exchange via shfl_xor(16,32) ----
    float s = 0.f;
#pragma unroll
    for (int i = 0; i < 16; i++) s += xv[i].x + xv[i].y + xv[i].z + xv[i].w;
    s += __shfl_xor(s, 16);
    s += __shfl_xor(s, 32);
    float mean = s * (1.f / 256.f);
    float q = 0.f;
#pragma unroll
    for (int i = 0; i < 16; i++) {
        float a0 = xv[i].x - mean, a1 = xv[i].y - mean;
        float a2 = xv[i].z - mean, a3 = xv[i].w - mean;
        q += a0 * a0 + a1 * a1 + a2 * a2 + a3 * a3;
    }
    q += __shfl_xor(q, 16);
    q += __shfl_xor(q, 32);
    float rs = rsqrtf(q * (1.f / 256.f) + 1e-5f);

    bf16x8 aF[8];
#pragma unroll
    for (int ks = 0; ks < 8; ks++) {
        const int kb = ks * 32 + quad * 8;
        float y0 = (xv[2 * ks].x - mean) * rs * lnwl[kb + 0] + lnbl[kb + 0];
        float y1 = (xv[2 * ks].y - mean) * rs * lnwl[kb + 1] + lnbl[kb + 1];
        float y2 = (xv[2 * ks].z - mean) * rs * lnwl[kb + 2] + lnbl[kb + 2];
        float y3 = (xv[2 * ks].w - mean) * rs * lnwl[kb + 3] + lnbl[kb + 3];
        float y4 = (xv[2 * ks + 1].x - mean) * rs * lnwl[kb + 4] + lnbl[kb + 4];
        float y5 = (xv[2 * ks + 1].y - mean) * rs * lnwl[kb + 5] + lnbl[kb + 5];
        float y6 = (xv[2 * ks + 1].z - mean) * rs * lnwl[kb + 6] + lnbl[kb + 6];
        float y7 = (xv[2 * ks + 1].w - mean) * rs * lnwl[kb + 7] + lnbl[kb + 7];
        u32x4 up;
        up.x = cvtpk_bf16(y0, y1);
        up.y = cvtpk_bf16(y2, y3);
        up.z = cvtpk_bf16(y4, y5);
        up.w = cvtpk_bf16(y6, y7);
        aF[ks] = __builtin_bit_cast(bf16x8, up);
    }

    for (int ch = 0; ch < 16; ch++) {
        // ---- GEMM1: H(64x64) = A(64x256) @ W1[ch]^T ----
        f32x4 acc1[4];
#pragma unroll
        for (int j = 0; j < 4; j++) acc1[j] = (f32x4){0.f, 0.f, 0.f, 0.f};
#pragma unroll
        for (int ks = 0; ks < 8; ks++) {
            bf16x8 bF[4];
#pragma unroll
            for (int j = 0; j < 4; j++)
                bF[j] = *(const bf16x8*)&W1l[(ks * 4 + quad) * 512 + (j * 16 + l15) * 8];
#pragma unroll
            for (int j = 0; j < 4; j++)
                acc1[j] = __builtin_amdgcn_mfma_f32_16x16x32_bf16(bF[j], aF[ks], acc1[j], 0, 0, 0);
        }
        // ---- bias + gelu -> H LDS (GEMM2-fragment order) ----
#pragma unroll
        for (int j = 0; j < 4; j++) {
            float4 b1v = *(const float4*)&b1l[ch * 64 + j * 16 + quad * 4];
            f32x4 rv = acc1[j];
            rv[0] = gelu_t(rv[0] + b1v.x);
            rv[1] = gelu_t(rv[1] + b1v.y);
            rv[2] = gelu_t(rv[2] + b1v.z);
            rv[3] = gelu_t(rv[3] + b1v.w);
            int h = j * 16 + quad * 4;
            uint2 pk;
            pk.x = cvtpk_bf16(rv[0], rv[1]);
            pk.y = cvtpk_bf16(rv[2], rv[3]);
            *(uint2*)&Hl[((h >> 3) * 64 + (w * 16 + l15)) * 8 + (h & 7)] = pk;
        }
        asm volatile("s_waitcnt lgkmcnt(0)" ::: "memory");  // W1 reads + H writes done
        __builtin_amdgcn_sched_barrier(0);
        __builtin_amdgcn_s_barrier();          // B1: W1l free; H visible
        if (ch + 1 < 16) {
            SW1(ch + 1);                        // 8 loads into W1l
            asm volatile("s_waitcnt vmcnt(8)" ::: "memory"); // SW2(ch) landed
        } else {
            asm volatile("s_waitcnt vmcnt(0)" ::: "memory");
        }
        __builtin_amdgcn_s_barrier();          // B2: W2[ch] visible to all

        // ---- GEMM2: acc2 += H(64x64) @ W2[ch]^T (wave w owns n-cols
        //      [nh*128 + w*32, +32)) ----
        __builtin_amdgcn_s_setprio(1);
#pragma unroll
        for (int ks2 = 0; ks2 < 2; ks2++) {
            bf16x8 a2[4], b2f[2];
#pragma unroll
            for (int i = 0; i < 4; i++)
                a2[i] = *(const bf16x8*)&Hl[(ks2 * 4 + quad) * 512 + (i * 16 + l15) * 8];
#pragma unroll
            for (int j = 0; j < 2; j++)
                b2f[j] = *(const bf16x8*)&W2l[(ks2 * 4 + quad) * 1024 + (w * 32 + j * 16 + l15) * 8];
#pragma unroll
            for (int i = 0; i < 4; i++)
#pragma unroll
                for (int j = 0; j < 2; j++)
                    acc2[i][j] = __builtin_amdgcn_mfma_f32_16x16x32_bf16(b2f[j], a2[i], acc2[i][j], 0, 0, 0);
        }
        __builtin_amdgcn_s_setprio(0);
        asm volatile("s_waitcnt lgkmcnt(0)" ::: "memory");  // W2/H reads retired
        __builtin_amdgcn_sched_barrier(0);
        __builtin_amdgcn_s_barrier();          // B3: W2l + Hl free
        if (ch + 1 < 16) {
            SW2(ch + 1);                        // 4 loads into W2l
            asm volatile("s_waitcnt vmcnt(4)" ::: "memory"); // SW1(ch+1) landed
            __builtin_amdgcn_s_barrier();      // B4: W1[ch+1] visible to all
        }
    }

    // ---- epilogue: out = acc2 + b2 + X ----
#pragma unroll
    for (int i = 0; i < 4; i++) {
        int mg = m0 + i * 16 + l15;
#pragma unroll
        for (int j = 0; j < 2; j++) {
            int ng = nh * 128 + w * 32 + j * 16 + quad * 4;
            f32x4 rv = acc2[i][j];
            float4 bv = *(const float4*)(b2 + ng);
            float4 rr = *(const float4*)(X + (size_t)mg * 256 + ng);
            rv[0] += bv.x + rr.x; rv[1] += bv.y + rr.y;
            rv[2] += bv.z + rr.z; rv[3] += bv.w + rr.w;
            *(float4*)(out + (size_t)mg * 256 + ng) =
                make_float4(rv[0], rv[1], rv[2], rv[3]);
        }
    }
}

// ---------------------------------------------------------------------------
// MFMA flash attention v2 (unchanged from R4).
// ---------------------------------------------------------------------------
__global__ __launch_bounds__(256, 4) void attn_mfma(const ushort_t* __restrict__ Qb,
                                                    const ushort_t* __restrict__ Kb,
                                                    const ushort_t* __restrict__ Vtg,
                                                    ushort_t* __restrict__ o) {
    int bh = blockIdx.x;
    int b = bh >> 3, h = bh & 7;
    int q0 = blockIdx.y * 128;
    int tid = threadIdx.x;
    int wave = tid >> 6, lane = tid & 63;
    int l15 = lane & 15, quad = lane >> 4;

    __shared__ __align__(16) ushort_t Ks[2][64][40];     // [buf][key][d]
    __shared__ __align__(16) ushort_t Vs[2][32][88];     // [buf][d][key]
    __shared__ __align__(16) ushort_t Ps[4][32][72];     // per wave [q][key]

    const size_t hb = (size_t)bh * 32768;

    bf16x8 qfrag[2];
#pragma unroll
    for (int g = 0; g < 2; g++)
        qfrag[g] = *(const bf16x8*)(Qb + hb + (size_t)(q0 + wave * 32 + g * 16 + l15) * 32 + quad * 8);

    f32x4 oa[2][2];
#pragma unroll
    for (int g = 0; g < 2; g++)
#pragma unroll
        for (int t = 0; t < 2; t++) oa[g][t] = (f32x4){0.f, 0.f, 0.f, 0.f};
    f32x4 ls[2];
    ls[0] = (f32x4){0.f, 0.f, 0.f, 0.f};
    ls[1] = (f32x4){0.f, 0.f, 0.f, 0.f};

    bf16x8 ones;
#pragma unroll
    for (int i = 0; i < 8; i++) ones[i] = (short)0x3F80;   // bf16 1.0

    int krow = tid >> 2, kch = tid & 3;
    int vrow = tid >> 3, vch = tid & 7;
    const ushort_t* kgp = Kb + hb + (size_t)krow * 32 + kch * 8;
    const ushort_t* vgp = Vtg + hb + (size_t)vrow * 1024 + vch * 8;

    // prefetch tile 0 into registers
    bf16x8 kreg = *(const bf16x8*)kgp;
    bf16x8 vreg = *(const bf16x8*)vgp;

#pragma unroll 2
    for (int kt = 0; kt < 16; kt++) {
        const int cur = kt & 1;
        *(bf16x8*)&Ks[cur][krow][kch * 8] = kreg;
        *(bf16x8*)&Vs[cur][vrow][vch * 8] = vreg;
        __syncthreads();
        if (kt < 15) {
            kreg = *(const bf16x8*)(kgp + (kt + 1) * 2048);
            vreg = *(const bf16x8*)(vgp + (kt + 1) * 64);
        }

        bf16x8 kf[4];
#pragma unroll
        for (int kg = 0; kg < 4; kg++)
            kf[kg] = *(const bf16x8*)&Ks[cur][kg * 16 + l15][quad * 8];

        const f32x4 z = {0.f, 0.f, 0.f, 0.f};
#pragma unroll
        for (int g = 0; g < 2; g++) {
#pragma unroll
            for (int kg = 0; kg < 4; kg++) {
                f32x4 st = __builtin_amdgcn_mfma_f32_16x16x32_bf16(kf[kg], qfrag[g], z, 0, 0, 0);
                float e0 = __builtin_amdgcn_exp2f(st[0]);
                float e1 = __builtin_amdgcn_exp2f(st[1]);
                float e2 = __builtin_amdgcn_exp2f(st[2]);
                float e3 = __builtin_amdgcn_exp2f(st[3]);
                uint2 pk;
                pk.x = cvtpk_bf16(e0, e1);
                pk.y = cvtpk_bf16(e2, e3);
                *(uint2*)&Ps[wave][g * 16 + l15][kg * 16 + quad * 4] = pk;
            }
        }

        __builtin_amdgcn_s_setprio(1);
#pragma unroll
        for (int c = 0; c < 2; c++) {
            bf16x8 vb0 = *(const bf16x8*)&Vs[cur][l15][c * 32 + quad * 8];
            bf16x8 vb1 = *(const bf16x8*)&Vs[cur][16 + l15][c * 32 + quad * 8];
#pragma unroll
            for (int g = 0; g < 2; g++) {
                bf16x8 pa = *(const bf16x8*)&Ps[wave][g * 16 + l15][c * 32 + quad * 8];
                oa[g][0] = __builtin_amdgcn_mfma_f32_16x16x32_bf16(pa, vb0, oa[g][0], 0, 0, 0);
                oa[g][1] = __builtin_amdgcn_mfma_f32_16x16x32_bf16(pa, vb1, oa[g][1], 0, 0, 0);
                ls[g]    = __builtin_amdgcn_mfma_f32_16x16x32_bf16(pa, ones, ls[g], 0, 0, 0);
            }
        }
        __builtin_amdgcn_s_setprio(0);
    }

#pragma unroll
    for (int g = 0; g < 2; g++) {
#pragma unroll
        for (int r = 0; r < 4; r++) {
            float inv = 1.f / ls[g][r];
            int q = q0 + wave * 32 + g * 16 + quad * 4 + r;
            ushort_t* orow = o + ((size_t)(b * 1024 + q)) * 256 + h * 32;
            orow[l15] = (ushort_t)f2bf(oa[g][0][r] * inv);
            orow[l15 + 16] = (ushort_t)f2bf(oa[g][1][r] * inv);
        }
    }
}

// ---------------------------------------------------------------------------
// Deformable gather -> bf16. One block per token, thread = (h=tid>>5, d=tid&31).
// ---------------------------------------------------------------------------
__global__ __launch_bounds__(256) void deform_kernel(const float* __restrict__ ref,
                                                     const float* __restrict__ off,
                                                     const float* __restrict__ awl,
                                                     const float* __restrict__ v,
                                                     ushort_t* __restrict__ out) {
    int t = blockIdx.x;
    int b = t >> 10;
    int tid = threadIdx.x;
    int h = tid >> 5, d = tid & 31;

    float rx = ref[(size_t)t * 2 + 0];
    float ry = ref[(size_t)t * 2 + 1];
    const float* offr = off + (size_t)t * 64 + h * 8;
    const float* awr = awl + (size_t)t * 32 + h * 4;

    float L0 = awr[0], L1 = awr[1], L2 = awr[2], L3 = awr[3];
    float mm = fmaxf(fmaxf(L0, L1), fmaxf(L2, L3));
    float e0 = __expf(L0 - mm), e1 = __expf(L1 - mm), e2 = __expf(L2 - mm), e3 = __expf(L3 - mm);
    float inv = 1.f / (e0 + e1 + e2 + e3);
    float aw[4] = {e0 * inv, e1 * inv, e2 * inv, e3 * inv};

    const float* vb = v + (size_t)b * Nq * Cq + h * 32 + d;

    float s = 0.f;
#pragma unroll
    for (int p = 0; p < 4; p++) {
        float gx = rx * 32.f + offr[p * 2 + 0] - 0.5f;
        float gy = ry * 32.f + offr[p * 2 + 1] - 0.5f;
        float x0f = floorf(gx), y0f = floorf(gy);
        float lx = gx - x0f, ly = gy - y0f;
        int x0 = (int)x0f, y0 = (int)y0f;
        auto g = [&](int xi, int yi) -> float {
            if (xi < 0 || xi > 31 || yi < 0 || yi > 31) return 0.f;
            return vb[(size_t)(yi * 32 + xi) * Cq];
        };
        float sp = g(x0, y0) * (1.f - lx) * (1.f - ly)
                 + g(x0 + 1, y0) * lx * (1.f - ly)
                 + g(x0, y0 + 1) * (1.f - lx) * ly
                 + g(x0 + 1, y0 + 1) * lx * ly;
        s += aw[p] * sp;
    }
    out[(size_t)t * Cq + h * 32 + d] = (ushort_t)f2bf(s);
}

// ---------------------------------------------------------------------------
// Launch
// ---------------------------------------------------------------------------
extern "C" void kernel_launch(void* const* d_in, const int* in_sizes, int n_in,
                              void* d_out, int out_size, void* d_ws, size_t ws_size,
                              hipStream_t stream) {
    const size_t S = (size_t)BNq * Cq;  // 4,194,304
    float* ws = (float*)d_ws;
    float* X = ws;                                  // [0, S) residual fp32
    ushort_t* Ybf = (ushort_t*)(ws + S);            // [S, 1.5S)
    ushort_t* Wbf = (ushort_t*)(ws + S + S / 2);    // [1.5S, 2S)

    ushort_t* Wqkv   = Wbf;
    ushort_t* Wproj  = Wbf + 196608;
    ushort_t* Woff   = Wbf + 262144;   // off(64 rows) + aw(32 rows) contiguous
    ushort_t* Waw    = Wbf + 278528;
    ushort_t* Wvproj = Wbf + 286720;
    ushort_t* Woproj = Wbf + 352256;
    ushort_t* Wfc1   = Wbf + 417792;
    ushort_t* Wfc2   = Wbf + 679936;

    ushort_t* QKVbf = (ushort_t*)(ws + 2 * S);              // Q,K,V^T: [2S, 3.5S)
    ushort_t* O1bf  = (ushort_t*)(ws + 2 * S + 3 * S / 2);  // [3.5S, 4S)
    float* Vb   = ws + 2 * S + S / 2;                       // [2.5S, 3.5S)
    float* OffB = ws + 2 * S + 3 * S / 2;                   // [3.5S, 3.75S)
    float* AwB  = OffB + (size_t)BNq * 64;                  // [3.75S, 3.875S)
    ushort_t* Sbbf = (ushort_t*)(AwB + (size_t)BNq * 32);   // [3.875S, 4.375S)
    ushort_t* Valbf = (ushort_t*)(ws + 9 * S / 2);          // [4.5S, 5S)

    auto fp = [&](int i) { return (const float*)d_in[i]; };
    const float* x_in = fp(0);

    // ---- all fp32->bf16 casts in one dispatch ----
    CastArgs ca;
    ca.s[0] = {fp(9),  Wqkv,   192, 196608};
    ca.s[1] = {fp(10), Wproj,  64,  65536};
    ca.s[2] = {fp(12), Woff,   16,  16384};
    ca.s[3] = {fp(14), Waw,    8,   8192};
    ca.s[4] = {fp(16), Wvproj, 64,  65536};
    ca.s[5] = {fp(18), Woproj, 64,  65536};
    ca.s[6] = {fp(20), Wfc1,   256, 262144};
    ca.s[7] = {fp(22), Wfc2,   256, 262144};
    ca.s[8] = {fp(2),  Valbf,  4096, (int)S};
    castm<<<5016, 256, 0, stream>>>(ca);

    // ---- stage 1: self-attention ----
    ln_kernel<<<BNq / 4, 256, 0, stream>>>(x_in, fp(3), fp(4), Ybf);
    mgemm<1, false, false, 256><<<dim3(128, 12), 256, 0, stream>>>(
        Ybf, Wqkv, nullptr, nullptr, QKVbf, BNq, 768);
    attn_mfma<<<dim3(128, 8), 256, 0, stream>>>(
        QKVbf, QKVbf + S, QKVbf + 2 * S, O1bf);
    mgemm<0, false, true, 256><<<dim3(128, 4), 256, 0, stream>>>(
        O1bf, Wproj, fp(11), x_in, X, BNq, 256);

    // ---- stage 2: deformable attention ----
    ln_kernel<<<BNq / 4, 256, 0, stream>>>(X, fp(5), fp(6), Ybf);
    mgemm<0, false, false, 256><<<dim3(128, 4), 256, 0, stream>>>(
        Valbf, Wvproj, fp(17), nullptr, Vb, BNq, 256);
    mgemm<3, false, false, 256><<<dim3(128, 2), 256, 0, stream>>>(
        Ybf, Woff, fp(13), fp(15), OffB, BNq, 96);
    deform_kernel<<<BNq, 256, 0, stream>>>(fp(1), OffB, AwB, Vb, Sbbf);
    mgemm<0, false, true, 256><<<dim3(128, 4), 256, 0, stream>>>(
        Sbbf, Woproj, fp(19), X, X, BNq, 256);

    // ---- stage 3: MLP (fused ln3+fc1+gelu+fc2+residual; H stays in LDS) ----
    mlp_fused<<<BNq / 32, 256, 0, stream>>>(
        X, Wfc1, fp(21), Wfc2, fp(23), fp(7), fp(8), (float*)d_out);
}

// Round 13
// 302.737 us; speedup vs baseline: 1.1157x; 1.0431x over previous
//
#include <hip/hip_runtime.h>
#include <hip/hip_bf16.h>

// Problem constants
#define Bq   16
#define Nq   1024
#define Cq   256
#define NHq  8
#define DHq  32
#define HIDq 1024
#define BNq  (Bq * Nq)   // 16384 tokens

typedef float f32x4 __attribute__((ext_vector_type(4)));
typedef short bf16x8 __attribute__((ext_vector_type(8)));
typedef unsigned int u32x4 __attribute__((ext_vector_type(4)));
typedef unsigned short ushort_t;

__device__ __forceinline__ unsigned int f2bf(float f) {   // RNE
    unsigned int u = __builtin_bit_cast(unsigned int, f);
    u = (u + 0x7fffu + ((u >> 16) & 1u)) >> 16;
    return u & 0xffffu;
}
// pack two floats -> two bf16 (round-half-up) in one dword via v_perm
__device__ __forceinline__ unsigned int packbf2(float a, float b) {
    unsigned int ua = __builtin_bit_cast(unsigned int, a) + 0x8000u;
    unsigned int ub = __builtin_bit_cast(unsigned int, b) + 0x8000u;
    return __builtin_amdgcn_perm(ub, ua, 0x07060302);
}
// single-instruction packed f32x2 -> bf16x2 (RNE); lo -> low half
__device__ __forceinline__ unsigned int cvtpk_bf16(float lo, float hi) {
    unsigned int r;
    asm("v_cvt_pk_bf16_f32 %0, %1, %2" : "=v"(r) : "v"(lo), "v"(hi));
    return r;
}
// branch-free tanh-approx GELU
__device__ __forceinline__ float gelu_t(float x) {
    float y = x * (0.7978845608028654f + 0.035677408136300125f * x * x);
    float e = __builtin_amdgcn_exp2f(y * 2.8853900817779268f);
    return x - x / (1.f + e);
}

typedef __attribute__((address_space(1))) const unsigned int* gas_u32;
typedef __attribute__((address_space(3))) unsigned int* las_u32;
__device__ __forceinline__ void gload16(const void* g, void* l) {
    __builtin_amdgcn_global_load_lds((gas_u32)g, (las_u32)l, 16, 0, 0);
}

// ---------------------------------------------------------------------------
// Fused fp32 -> bf16 casts: 9 segments in one dispatch.
// ---------------------------------------------------------------------------
struct CastSeg { const float* src; ushort_t* dst; int nblk; int n; };
struct CastArgs { CastSeg s[9]; };

__global__ __launch_bounds__(256) void castm(CastArgs a) {
    int bid = blockIdx.x;
    int seg = 0, acc = 0;
    for (seg = 0; seg < 9; seg++) {
        if (bid < acc + a.s[seg].nblk) break;
        acc += a.s[seg].nblk;
    }
    const CastSeg sg = a.s[seg];
    int i = (bid - acc) * 1024 + threadIdx.x * 4;
    if (i < sg.n) {
        float4 v = *(const float4*)(sg.src + i);
        uint2 u;
        u.x = packbf2(v.x, v.y);
        u.y = packbf2(v.z, v.w);
        *(uint2*)(sg.dst + i) = u;
    }
}

// ---------------------------------------------------------------------------
// MFMA GEMM with counted-vmcnt double-buffered pipeline (R4 structure —
// measured best for the small projection GEMMs). Used for proj/vproj/oproj.
// BM=128, BN=64, BK=64; 4 waves, wave w owns rows [w*32, w*32+32).
// ---------------------------------------------------------------------------
template <int OMODE, bool GELU_, bool RESID, int KT>
__global__ __launch_bounds__(256) void mgemm(const ushort_t* __restrict__ A,
                                             const ushort_t* __restrict__ W,
                                             const float* __restrict__ bias,
                                             const float* __restrict__ R,
                                             void* __restrict__ OutP,
                                             int M, int Nn) {
    __shared__ __align__(16) ushort_t Al[2][8192];
    __shared__ __align__(16) ushort_t Bl[2][4096];
    int m0 = blockIdx.x * 128, n0 = blockIdx.y * 64;
    int tid = threadIdx.x;
    int w = tid >> 6, lane = tid & 63;
    int l15 = lane & 15, quad = lane >> 4;

    f32x4 acc[2][4];
#pragma unroll
    for (int i = 0; i < 2; i++)
#pragma unroll
        for (int j = 0; j < 4; j++) acc[i][j] = (f32x4){0.f, 0.f, 0.f, 0.f};

    const ushort_t* gA0 = A + (size_t)(m0 + lane) * KT + w * 8;
    const ushort_t* gA1 = gA0 + (size_t)64 * KT;
    const ushort_t* gB0 = W + (size_t)(n0 + lane) * KT + w * 8;

    auto STAGE = [&](int buf, int t) {
        const int k0 = t * 64;
        gload16(gA0 + k0,      &Al[buf][w * 1024]);
        gload16(gA1 + k0,      &Al[buf][w * 1024 + 512]);
        gload16(gA0 + k0 + 32, &Al[buf][(w + 4) * 1024]);
        gload16(gA1 + k0 + 32, &Al[buf][(w + 4) * 1024 + 512]);
        gload16(gB0 + k0,      &Bl[buf][w * 512]);
        gload16(gB0 + k0 + 32, &Bl[buf][(w + 4) * 512]);
    };

    constexpr int NT = KT / 64;
    STAGE(0, 0);
    STAGE(1, 1);
    asm volatile("s_waitcnt vmcnt(6)" ::: "memory");   // tile 0 landed
    __builtin_amdgcn_s_barrier();

#pragma unroll
    for (int t = 0; t < NT; t++) {
        const int cur = t & 1;
        bf16x8 aF[2][2], bF[2][4];
#pragma unroll
        for (int ks = 0; ks < 2; ks++) {
#pragma unroll
            for (int i = 0; i < 2; i++)
                aF[ks][i] = *(const bf16x8*)&Al[cur][(ks * 4 + quad) * 1024 + (w * 32 + i * 16 + l15) * 8];
#pragma unroll
            for (int j = 0; j < 4; j++)
                bF[ks][j] = *(const bf16x8*)&Bl[cur][(ks * 4 + quad) * 512 + (j * 16 + l15) * 8];
        }
        asm volatile("s_waitcnt lgkmcnt(0)" ::: "memory");
        __builtin_amdgcn_sched_barrier(0);
        __builtin_amdgcn_s_barrier();        // all waves done reading cur
        if (t + 2 < NT) STAGE(cur, t + 2);

        __builtin_amdgcn_s_setprio(1);
#pragma unroll
        for (int ks = 0; ks < 2; ks++)
#pragma unroll
            for (int i = 0; i < 2; i++)
#pragma unroll
                for (int j = 0; j < 4; j++)
                    acc[i][j] = __builtin_amdgcn_mfma_f32_16x16x32_bf16(bF[ks][j], aF[ks][i], acc[i][j], 0, 0, 0);
        __builtin_amdgcn_s_setprio(0);

        if (t + 2 < NT) {
            asm volatile("s_waitcnt vmcnt(6)" ::: "memory");
        } else if (t + 1 < NT) {
            asm volatile("s_waitcnt vmcnt(0)" ::: "memory");
        }
        if (t + 1 < NT) __builtin_amdgcn_s_barrier();
    }

#pragma unroll
    for (int i = 0; i < 2; i++) {
        int mg = m0 + w * 32 + i * 16 + l15;
#pragma unroll
        for (int j = 0; j < 4; j++) {
            int ng = n0 + j * 16 + quad * 4;
            f32x4 rv = acc[i][j];
            if (bias) {
                float4 bv = *(const float4*)(bias + ng);
                rv[0] += bv.x; rv[1] += bv.y; rv[2] += bv.z; rv[3] += bv.w;
            }
            if (GELU_) {
#pragma unroll
                for (int r = 0; r < 4; r++) rv[r] = gelu_t(rv[r]);
            }
            if constexpr (OMODE == 2) {
                uint2 pk;
                pk.x = packbf2(rv[0], rv[1]);
                pk.y = packbf2(rv[2], rv[3]);
                *(uint2*)((ushort_t*)OutP + (size_t)mg * Nn + ng) = pk;
            } else {
                if (RESID) {
                    float4 rr = *(const float4*)(R + (size_t)mg * Nn + ng);
                    rv[0] += rr.x; rv[1] += rr.y; rv[2] += rr.z; rv[3] += rr.w;
                }
                *(float4*)((float*)OutP + (size_t)mg * Nn + ng) =
                    make_float4(rv[0], rv[1], rv[2], rv[3]);
            }
        }
    }
}

// ---------------------------------------------------------------------------
// LN-fused register-A GEMM (lgemm): out = LN(X) @ W^T with OMODE epilogues.
// Structure = the R12-verified mlp_fused GEMM1: block = 64 m-rows, 4 waves,
// wave w holds rows w*16+l15 fully in registers (aF[8], k=ks*32+quad*8);
// LN3-style in-register LayerNorm (in-lane reduce + shfl_xor 16/32).
// W streamed through double-buffered LDS (2x32KB) in NCH chunks of 64 rows,
// counted-vmcnt ledger: prologue SW(0) -> ln,xv -> SW(1) -> vmcnt(8);
// per chunk: 32 MFMA -> EPI stores -> lgkm(0) -> barrier [Wl[cur] free] ->
// SW(ch+2) -> vmcnt(8) [drains SW(ch+1) + stores(ch); stores are older than
// SW(ch+2) in the FIFO so the count is store-independent] -> barrier.
// NSPLIT: n-groups of NCH*64 cols; block bid -> m = (bid/NSPLIT)*64,
// nb = (bid%NSPLIT)*NCH*64.
// OMODE 1: qkv -> bf16 head-major (Q scaled rsqrt(32)*log2e, V transposed
//          [bh][32][1024]) — epilogue mapping mg = m0+w*16+l15,
//          ng = nb+ch*64+j*16+quad*4 (same lane algebra as mgemm's).
// OMODE 3: fused off/aw (ng<64 -> OffB w/ bias; 64<=ng<96 -> AwB w/ R;
//          ng>=96 discarded — W rows 96..127 read into adjacent Wvproj
//          region, memory-valid, results dropped).
// ---------------------------------------------------------------------------
template <int OMODE, int NCH, int NSPLIT>
__global__ __launch_bounds__(256) void lgemm(const float* __restrict__ X,
                                             const ushort_t* __restrict__ W,
                                             const float* __restrict__ bias,
                                             const float* __restrict__ R,
                                             const float* __restrict__ lnw,
                                             const float* __restrict__ lnb,
                                             void* __restrict__ OutP) {
    __shared__ __align__(16) ushort_t Wl[2][16384];    // 64 KB
    __shared__ __align__(16) float lnwl[256];          // 1 KB
    __shared__ __align__(16) float lnbl[256];          // 1 KB
    int bid = blockIdx.x;
    int m0 = (bid / NSPLIT) * 64;
    int nb = (bid % NSPLIT) * (NCH * 64);
    int tid = threadIdx.x;
    int w = tid >> 6, lane = tid & 63;
    int l15 = lane & 15, quad = lane >> 4;

    // stage W chunk ch (64 n-rows x 256 k): wave w stages kc = w + 4j  [8 loads]
    auto SW = [&](int buf, int ch) {
        const ushort_t* g = W + (size_t)(nb + ch * 64 + lane) * 256 + w * 8;
#pragma unroll
        for (int j = 0; j < 8; j++)
            gload16(g + j * 32, &Wl[buf][(w + 4 * j) * 512]);
    };

    // prologue: SW(0) -> ln params -> X rows -> SW(1) -> vmcnt(8) leaves SW(1)
    SW(0, 0);
    if (w == 0) gload16(lnw + lane * 4, &lnwl[0]);
    if (w == 1) gload16(lnb + lane * 4, &lnbl[0]);
    float4 xv[16];
    {
        const float* gx = X + (size_t)(m0 + w * 16 + l15) * 256 + quad * 8;
#pragma unroll
        for (int ks = 0; ks < 8; ks++) {
            xv[2 * ks]     = *(const float4*)(gx + ks * 32);
            xv[2 * ks + 1] = *(const float4*)(gx + ks * 32 + 4);
        }
    }
    if (NCH > 1) SW(1, 1);
    if (NCH > 1) { asm volatile("s_waitcnt vmcnt(8)" ::: "memory"); }
    else         { asm volatile("s_waitcnt vmcnt(0)" ::: "memory"); }
    __builtin_amdgcn_s_barrier();

    // ---- in-register LayerNorm (R12-verified pattern) ----
    float s = 0.f;
#pragma unroll
    for (int i = 0; i < 16; i++) s += xv[i].x + xv[i].y + xv[i].z + xv[i].w;
    s += __shfl_xor(s, 16);
    s += __shfl_xor(s, 32);
    float mean = s * (1.f / 256.f);
    float q = 0.f;
#pragma unroll
    for (int i = 0; i < 16; i++) {
        float a0 = xv[i].x - mean, a1 = xv[i].y - mean;
        float a2 = xv[i].z - mean, a3 = xv[i].w - mean;
        q += a0 * a0 + a1 * a1 + a2 * a2 + a3 * a3;
    }
    q += __shfl_xor(q, 16);
    q += __shfl_xor(q, 32);
    float rs = rsqrtf(q * (1.f / 256.f) + 1e-5f);

    bf16x8 aF[8];
#pragma unroll
    for (int ks = 0; ks < 8; ks++) {
        const int kb = ks * 32 + quad * 8;
        float y0 = (xv[2 * ks].x - mean) * rs * lnwl[kb + 0] + lnbl[kb + 0];
        float y1 = (xv[2 * ks].y - mean) * rs * lnwl[kb + 1] + lnbl[kb + 1];
        float y2 = (xv[2 * ks].z - mean) * rs * lnwl[kb + 2] + lnbl[kb + 2];
        float y3 = (xv[2 * ks].w - mean) * rs * lnwl[kb + 3] + lnbl[kb + 3];
        float y4 = (xv[2 * ks + 1].x - mean) * rs * lnwl[kb + 4] + lnbl[kb + 4];
        float y5 = (xv[2 * ks + 1].y - mean) * rs * lnwl[kb + 5] + lnbl[kb + 5];
        float y6 = (xv[2 * ks + 1].z - mean) * rs * lnwl[kb + 6] + lnbl[kb + 6];
        float y7 = (xv[2 * ks + 1].w - mean) * rs * lnwl[kb + 7] + lnbl[kb + 7];
        u32x4 up;
        up.x = cvtpk_bf16(y0, y1);
        up.y = cvtpk_bf16(y2, y3);
        up.z = cvtpk_bf16(y4, y5);
        up.w = cvtpk_bf16(y6, y7);
        aF[ks] = __builtin_bit_cast(bf16x8, up);
    }

#pragma unroll
    for (int ch = 0; ch < NCH; ch++) {
        const int cur = ch & 1;
        f32x4 acc[4];
#pragma unroll
        for (int j = 0; j < 4; j++) acc[j] = (f32x4){0.f, 0.f, 0.f, 0.f};
        __builtin_amdgcn_s_setprio(1);
#pragma unroll
        for (int ks = 0; ks < 8; ks++) {
            bf16x8 bF[4];
#pragma unroll
            for (int j = 0; j < 4; j++)
                bF[j] = *(const bf16x8*)&Wl[cur][(ks * 4 + quad) * 512 + (j * 16 + l15) * 8];
#pragma unroll
            for (int j = 0; j < 4; j++)
                acc[j] = __builtin_amdgcn_mfma_f32_16x16x32_bf16(bF[j], aF[ks], acc[j], 0, 0, 0);
        }
        __builtin_amdgcn_s_setprio(0);

        // ---- epilogue for this chunk ----
        int mg = m0 + w * 16 + l15;
#pragma unroll
        for (int j = 0; j < 4; j++) {
            int ng = nb + ch * 64 + j * 16 + quad * 4;
            f32x4 rv = acc[j];
            if constexpr (OMODE == 1) {
                int which = ng >> 8;
                int h = (ng >> 5) & 7;
                int d = ng & 31;
                int bb = mg >> 10, nn = mg & 1023;
                ushort_t* qb = (ushort_t*)OutP;
                if (which == 2) {          // V transposed: [bh][d][n]
                    size_t dst = 2 * (size_t)BNq * Cq +
                                 ((size_t)(bb * 8 + h) * 32 + d) * 1024 + nn;
#pragma unroll
                    for (int r = 0; r < 4; r++)
                        qb[dst + (size_t)r * 1024] = (ushort_t)f2bf(rv[r]);
                } else {
                    if (which == 0) {
                        const float sc = 0.17677669529663687f * 1.4426950408889634f;
                        rv[0] *= sc; rv[1] *= sc; rv[2] *= sc; rv[3] *= sc;
                    }
                    size_t dst = (size_t)which * ((size_t)BNq * Cq) +
                                 ((size_t)(bb * 8 + h) * 1024 + nn) * 32 + d;
                    uint2 pk;
                    pk.x = packbf2(rv[0], rv[1]);
                    pk.y = packbf2(rv[2], rv[3]);
                    *(uint2*)(qb + dst) = pk;
                }
            } else {                       // OMODE 3: off/aw
                if (ng >= 96) continue;
                if (ng < 64) {
                    float4 bv = *(const float4*)(bias + ng);
                    rv[0] += bv.x; rv[1] += bv.y; rv[2] += bv.z; rv[3] += bv.w;
                    *(float4*)((float*)OutP + (size_t)mg * 64 + ng) =
                        make_float4(rv[0], rv[1], rv[2], rv[3]);
                } else {
                    float4 bv = *(const float4*)(R + (ng - 64));
                    rv[0] += bv.x; rv[1] += bv.y; rv[2] += bv.z; rv[3] += bv.w;
                    *(float4*)((float*)OutP + (size_t)BNq * 64 + (size_t)mg * 32 + (ng - 64)) =
                        make_float4(rv[0], rv[1], rv[2], rv[3]);
                }
            }
        }

        asm volatile("s_waitcnt lgkmcnt(0)" ::: "memory");  // Wl[cur] reads done
        __builtin_amdgcn_sched_barrier(0);
        __builtin_amdgcn_s_barrier();        // Wl[cur] free for overwrite
        if (ch + 2 < NCH) {
            SW(cur, ch + 2);
            asm volatile("s_waitcnt vmcnt(8)" ::: "memory"); // SW(ch+1) landed
        } else if (ch + 1 < NCH) {
            asm volatile("s_waitcnt vmcnt(0)" ::: "memory");
        }
        if (ch + 1 < NCH) __builtin_amdgcn_s_barrier();     // W[ch+1] visible
    }
}

// ---------------------------------------------------------------------------
// Fused MLP v4 (unchanged from R12): out = X + gelu(LN3(X)@W1^T+b1)@W2^T+b2.
// ---------------------------------------------------------------------------
__global__ __launch_bounds__(256) void mlp_fused(const float* __restrict__ X,
                                                 const ushort_t* __restrict__ W1,
                                                 const float* __restrict__ b1,
                                                 const ushort_t* __restrict__ W2,
                                                 const float* __restrict__ b2,
                                                 const float* __restrict__ lnw,
                                                 const float* __restrict__ lnb,
                                                 float* __restrict__ out) {
    __shared__ __align__(16) ushort_t W1l[16384];      // 32 KB
    __shared__ __align__(16) ushort_t W2l[8192];       // 16 KB (n-half)
    __shared__ __align__(16) ushort_t Hl[4096];        // 8 KB
    __shared__ __align__(16) float b1l[1024];          // 4 KB
    __shared__ __align__(16) float lnwl[256];          // 1 KB
    __shared__ __align__(16) float lnbl[256];          // 1 KB
    int bid = blockIdx.x;
    int m0 = (bid >> 1) * 64;
    int nh = bid & 1;                  // output n-half: [nh*128, nh*128+128)
    int tid = threadIdx.x;
    int w = tid >> 6, lane = tid & 63;
    int l15 = lane & 15, quad = lane >> 4;

    auto SW1 = [&](int ch) {
        const ushort_t* g = W1 + (size_t)(ch * 64 + lane) * 256 + w * 8;
#pragma unroll
        for (int j = 0; j < 8; j++)
            gload16(g + j * 32, &W1l[(w + 4 * j) * 512]);
    };
    auto SW2 = [&](int ch) {
#pragma unroll
        for (int jj = 0; jj < 4; jj++) {
            const int kc2 = (jj & 1) * 4 + w;
            const int rj = jj >> 1;
            const ushort_t* g = W2 + (size_t)(nh * 128 + rj * 64 + lane) * 1024 +
                                ch * 64 + (kc2 & 3) * 8 + (kc2 >> 2) * 32;
            gload16(g, &W2l[kc2 * 1024 + rj * 512]);
        }
    };

    f32x4 acc2[4][2];
#pragma unroll
    for (int i = 0; i < 4; i++)
#pragma unroll
        for (int j = 0; j < 2; j++) acc2[i][j] = (f32x4){0.f, 0.f, 0.f, 0.f};

    SW1(0);
    SW2(0);
    gload16(b1 + w * 256 + lane * 4, &b1l[w * 256]);   // bias -> LDS
    if (w == 0) gload16(lnw + lane * 4, &lnwl[0]);     // ln weight -> LDS
    if (w == 1) gload16(lnb + lane * 4, &lnbl[0]);     // ln bias -> LDS

    float4 xv[16];
    {
        const float* gx = X + (size_t)(m0 + w * 16 + l15) * 256 + quad * 8;
#pragma unroll
        for (int ks = 0; ks < 8; ks++) {
            xv[2 * ks]     = *(const float4*)(gx + ks * 32);
            xv[2 * ks + 1] = *(const float4*)(gx + ks * 32 + 4);
        }
    }
    asm volatile("s_waitcnt vmcnt(0)" ::: "memory");
    __builtin_amdgcn_s_barrier();

    float s = 0.f;
#pragma unroll
    for (int i = 0; i < 16; i++) s += xv[i].x + xv[i].y + xv[i].z + xv[i].w;
    s += __shfl_xor(s, 16);
    s += __shfl_xor(s, 32);
    float mean = s * (1.f / 256.f);
    float q = 0.f;
#pragma unroll
    for (int i = 0; i < 16; i++) {
        float a0 = xv[i].x - mean, a1 = xv[i].y - mean;
        float a2 = xv[i].z - mean, a3 = xv[i].w - mean;
        q += a0 * a0 + a1 * a1 + a2 * a2 + a3 * a3;
    }
    q += __shfl_xor(q, 16);
    q += __shfl_xor(q, 32);
    float rs = rsqrtf(q * (1.f / 256.f) + 1e-5f);

    bf16x8 aF[8];
#pragma unroll
    for (int ks = 0; ks < 8; ks++) {
        const int kb = ks * 32 + quad * 8;
        float y0 = (xv[2 * ks].x - mean) * rs * lnwl[kb + 0] + lnbl[kb + 0];
        float y1 = (xv[2 * ks].y - mean) * rs * lnwl[kb + 1] + lnbl[kb + 1];
        float y2 = (xv[2 * ks].z - mean) * rs * lnwl[kb + 2] + lnbl[kb + 2];
        float y3 = (xv[2 * ks].w - mean) * rs * lnwl[kb + 3] + lnbl[kb + 3];
        float y4 = (xv[2 * ks + 1].x - mean) * rs * lnwl[kb + 4] + lnbl[kb + 4];
        float y5 = (xv[2 * ks + 1].y - mean) * rs * lnwl[kb + 5] + lnbl[kb + 5];
        float y6 = (xv[2 * ks + 1].z - mean) * rs * lnwl[kb + 6] + lnbl[kb + 6];
        float y7 = (xv[2 * ks + 1].w - mean) * rs * lnwl[kb + 7] + lnbl[kb + 7];
        u32x4 up;
        up.x = cvtpk_bf16(y0, y1);
        up.y = cvtpk_bf16(y2, y3);
        up.z = cvtpk_bf16(y4, y5);
        up.w = cvtpk_bf16(y6, y7);
        aF[ks] = __builtin_bit_cast(bf16x8, up);
    }

    for (int ch = 0; ch < 16; ch++) {
        f32x4 acc1[4];
#pragma unroll
        for (int j = 0; j < 4; j++) acc1[j] = (f32x4){0.f, 0.f, 0.f, 0.f};
#pragma unroll
        for (int ks = 0; ks < 8; ks++) {
            bf16x8 bF[4];
#pragma unroll
            for (int j = 0; j < 4; j++)
                bF[j] = *(const bf16x8*)&W1l[(ks * 4 + quad) * 512 + (j * 16 + l15) * 8];
#pragma unroll
            for (int j = 0; j < 4; j++)
                acc1[j] = __builtin_amdgcn_mfma_f32_16x16x32_bf16(bF[j], aF[ks], acc1[j], 0, 0, 0);
        }
#pragma unroll
        for (int j = 0; j < 4; j++) {
            float4 b1v = *(const float4*)&b1l[ch * 64 + j * 16 + quad * 4];
            f32x4 rv = acc1[j];
            rv[0] = gelu_t(rv[0] + b1v.x);
            rv[1] = gelu_t(rv[1] + b1v.y);
            rv[2] = gelu_t(rv[2] + b1v.z);
            rv[3] = gelu_t(rv[3] + b1v.w);
            int h = j * 16 + quad * 4;
            uint2 pk;
            pk.x = cvtpk_bf16(rv[0], rv[1]);
            pk.y = cvtpk_bf16(rv[2], rv[3]);
            *(uint2*)&Hl[((h >> 3) * 64 + (w * 16 + l15)) * 8 + (h & 7)] = pk;
        }
        asm volatile("s_waitcnt lgkmcnt(0)" ::: "memory");
        __builtin_amdgcn_sched_barrier(0);
        __builtin_amdgcn_s_barrier();          // B1: W1l free; H visible
        if (ch + 1 < 16) {
            SW1(ch + 1);
            asm volatile("s_waitcnt vmcnt(8)" ::: "memory"); // SW2(ch) landed
        } else {
            asm volatile("s_waitcnt vmcnt(0)" ::: "memory");
        }
        __builtin_amdgcn_s_barrier();          // B2: W2[ch] visible

        __builtin_amdgcn_s_setprio(1);
#pragma unroll
        for (int ks2 = 0; ks2 < 2; ks2++) {
            bf16x8 a2[4], b2f[2];
#pragma unroll
            for (int i = 0; i < 4; i++)
                a2[i] = *(const bf16x8*)&Hl[(ks2 * 4 + quad) * 512 + (i * 16 + l15) * 8];
#pragma unroll
            for (int j = 0; j < 2; j++)
                b2f[j] = *(const bf16x8*)&W2l[(ks2 * 4 + quad) * 1024 + (w * 32 + j * 16 + l15) * 8];
#pragma unroll
            for (int i = 0; i < 4; i++)
#pragma unroll
                for (int j = 0; j < 2; j++)
                    acc2[i][j] = __builtin_amdgcn_mfma_f32_16x16x32_bf16(b2f[j], a2[i], acc2[i][j], 0, 0, 0);
        }
        __builtin_amdgcn_s_setprio(0);
        asm volatile("s_waitcnt lgkmcnt(0)" ::: "memory");
        __builtin_amdgcn_sched_barrier(0);
        __builtin_amdgcn_s_barrier();          // B3: W2l + Hl free
        if (ch + 1 < 16) {
            SW2(ch + 1);
            asm volatile("s_waitcnt vmcnt(4)" ::: "memory"); // SW1(ch+1) landed
            __builtin_amdgcn_s_barrier();      // B4: W1[ch+1] visible
        }
    }

#pragma unroll
    for (int i = 0; i < 4; i++) {
        int mg = m0 + i * 16 + l15;
#pragma unroll
        for (int j = 0; j < 2; j++) {
            int ng = nh * 128 + w * 32 + j * 16 + quad * 4;
            f32x4 rv = acc2[i][j];
            float4 bv = *(const float4*)(b2 + ng);
            float4 rr = *(const float4*)(X + (size_t)mg * 256 + ng);
            rv[0] += bv.x + rr.x; rv[1] += bv.y + rr.y;
            rv[2] += bv.z + rr.z; rv[3] += bv.w + rr.w;
            *(float4*)(out + (size_t)mg * 256 + ng) =
                make_float4(rv[0], rv[1], rv[2], rv[3]);
        }
    }
}

// ---------------------------------------------------------------------------
// MFMA flash attention v2 (unchanged from R4).
// ---------------------------------------------------------------------------
__global__ __launch_bounds__(256, 4) void attn_mfma(const ushort_t* __restrict__ Qb,
                                                    const ushort_t* __restrict__ Kb,
                                                    const ushort_t* __restrict__ Vtg,
                                                    ushort_t* __restrict__ o) {
    int bh = blockIdx.x;
    int b = bh >> 3, h = bh & 7;
    int q0 = blockIdx.y * 128;
    int tid = threadIdx.x;
    int wave = tid >> 6, lane = tid & 63;
    int l15 = lane & 15, quad = lane >> 4;

    __shared__ __align__(16) ushort_t Ks[2][64][40];     // [buf][key][d]
    __shared__ __align__(16) ushort_t Vs[2][32][88];     // [buf][d][key]
    __shared__ __align__(16) ushort_t Ps[4][32][72];     // per wave [q][key]

    const size_t hb = (size_t)bh * 32768;

    bf16x8 qfrag[2];
#pragma unroll
    for (int g = 0; g < 2; g++)
        qfrag[g] = *(const bf16x8*)(Qb + hb + (size_t)(q0 + wave * 32 + g * 16 + l15) * 32 + quad * 8);

    f32x4 oa[2][2];
#pragma unroll
    for (int g = 0; g < 2; g++)
#pragma unroll
        for (int t = 0; t < 2; t++) oa[g][t] = (f32x4){0.f, 0.f, 0.f, 0.f};
    f32x4 ls[2];
    ls[0] = (f32x4){0.f, 0.f, 0.f, 0.f};
    ls[1] = (f32x4){0.f, 0.f, 0.f, 0.f};

    bf16x8 ones;
#pragma unroll
    for (int i = 0; i < 8; i++) ones[i] = (short)0x3F80;   // bf16 1.0

    int krow = tid >> 2, kch = tid & 3;
    int vrow = tid >> 3, vch = tid & 7;
    const ushort_t* kgp = Kb + hb + (size_t)krow * 32 + kch * 8;
    const ushort_t* vgp = Vtg + hb + (size_t)vrow * 1024 + vch * 8;

    // prefetch tile 0 into registers
    bf16x8 kreg = *(const bf16x8*)kgp;
    bf16x8 vreg = *(const bf16x8*)vgp;

#pragma unroll 2
    for (int kt = 0; kt < 16; kt++) {
        const int cur = kt & 1;
        *(bf16x8*)&Ks[cur][krow][kch * 8] = kreg;
        *(bf16x8*)&Vs[cur][vrow][vch * 8] = vreg;
        __syncthreads();
        if (kt < 15) {
            kreg = *(const bf16x8*)(kgp + (kt + 1) * 2048);
            vreg = *(const bf16x8*)(vgp + (kt + 1) * 64);
        }

        bf16x8 kf[4];
#pragma unroll
        for (int kg = 0; kg < 4; kg++)
            kf[kg] = *(const bf16x8*)&Ks[cur][kg * 16 + l15][quad * 8];

        const f32x4 z = {0.f, 0.f, 0.f, 0.f};
#pragma unroll
        for (int g = 0; g < 2; g++) {
#pragma unroll
            for (int kg = 0; kg < 4; kg++) {
                f32x4 st = __builtin_amdgcn_mfma_f32_16x16x32_bf16(kf[kg], qfrag[g], z, 0, 0, 0);
                float e0 = __builtin_amdgcn_exp2f(st[0]);
                float e1 = __builtin_amdgcn_exp2f(st[1]);
                float e2 = __builtin_amdgcn_exp2f(st[2]);
                float e3 = __builtin_amdgcn_exp2f(st[3]);
                uint2 pk;
                pk.x = cvtpk_bf16(e0, e1);
                pk.y = cvtpk_bf16(e2, e3);
                *(uint2*)&Ps[wave][g * 16 + l15][kg * 16 + quad * 4] = pk;
            }
        }

        __builtin_amdgcn_s_setprio(1);
#pragma unroll
        for (int c = 0; c < 2; c++) {
            bf16x8 vb0 = *(const bf16x8*)&Vs[cur][l15][c * 32 + quad * 8];
            bf16x8 vb1 = *(const bf16x8*)&Vs[cur][16 + l15][c * 32 + quad * 8];
#pragma unroll
            for (int g = 0; g < 2; g++) {
                bf16x8 pa = *(const bf16x8*)&Ps[wave][g * 16 + l15][c * 32 + quad * 8];
                oa[g][0] = __builtin_amdgcn_mfma_f32_16x16x32_bf16(pa, vb0, oa[g][0], 0, 0, 0);
                oa[g][1] = __builtin_amdgcn_mfma_f32_16x16x32_bf16(pa, vb1, oa[g][1], 0, 0, 0);
                ls[g]    = __builtin_amdgcn_mfma_f32_16x16x32_bf16(pa, ones, ls[g], 0, 0, 0);
            }
        }
        __builtin_amdgcn_s_setprio(0);
    }

#pragma unroll
    for (int g = 0; g < 2; g++) {
#pragma unroll
        for (int r = 0; r < 4; r++) {
            float inv = 1.f / ls[g][r];
            int q = q0 + wave * 32 + g * 16 + quad * 4 + r;
            ushort_t* orow = o + ((size_t)(b * 1024 + q)) * 256 + h * 32;
            orow[l15] = (ushort_t)f2bf(oa[g][0][r] * inv);
            orow[l15 + 16] = (ushort_t)f2bf(oa[g][1][r] * inv);
        }
    }
}

// ---------------------------------------------------------------------------
// Deformable gather -> bf16. One block per token, thread = (h=tid>>5, d=tid&31).
// ---------------------------------------------------------------------------
__global__ __launch_bounds__(256) void deform_kernel(const float* __restrict__ ref,
                                                     const float* __restrict__ off,
                                                     const float* __restrict__ awl,
                                                     const float* __restrict__ v,
                                                     ushort_t* __restrict__ out) {
    int t = blockIdx.x;
    int b = t >> 10;
    int tid = threadIdx.x;
    int h = tid >> 5, d = tid & 31;

    float rx = ref[(size_t)t * 2 + 0];
    float ry = ref[(size_t)t * 2 + 1];
    const float* offr = off + (size_t)t * 64 + h * 8;
    const float* awr = awl + (size_t)t * 32 + h * 4;

    float L0 = awr[0], L1 = awr[1], L2 = awr[2], L3 = awr[3];
    float mm = fmaxf(fmaxf(L0, L1), fmaxf(L2, L3));
    float e0 = __expf(L0 - mm), e1 = __expf(L1 - mm), e2 = __expf(L2 - mm), e3 = __expf(L3 - mm);
    float inv = 1.f / (e0 + e1 + e2 + e3);
    float aw[4] = {e0 * inv, e1 * inv, e2 * inv, e3 * inv};

    const float* vb = v + (size_t)b * Nq * Cq + h * 32 + d;

    float s = 0.f;
#pragma unroll
    for (int p = 0; p < 4; p++) {
        float gx = rx * 32.f + offr[p * 2 + 0] - 0.5f;
        float gy = ry * 32.f + offr[p * 2 + 1] - 0.5f;
        float x0f = floorf(gx), y0f = floorf(gy);
        float lx = gx - x0f, ly = gy - y0f;
        int x0 = (int)x0f, y0 = (int)y0f;
        auto g = [&](int xi, int yi) -> float {
            if (xi < 0 || xi > 31 || yi < 0 || yi > 31) return 0.f;
            return vb[(size_t)(yi * 32 + xi) * Cq];
        };
        float sp = g(x0, y0) * (1.f - lx) * (1.f - ly)
                 + g(x0 + 1, y0) * lx * (1.f - ly)
                 + g(x0, y0 + 1) * (1.f - lx) * ly
                 + g(x0 + 1, y0 + 1) * lx * ly;
        s += aw[p] * sp;
    }
    out[(size_t)t * Cq + h * 32 + d] = (ushort_t)f2bf(s);
}

// ---------------------------------------------------------------------------
// Launch
// ---------------------------------------------------------------------------
extern "C" void kernel_launch(void* const* d_in, const int* in_sizes, int n_in,
                              void* d_out, int out_size, void* d_ws, size_t ws_size,
                              hipStream_t stream) {
    const size_t S = (size_t)BNq * Cq;  // 4,194,304
    float* ws = (float*)d_ws;
    float* X = ws;                                  // [0, S) residual fp32
    ushort_t* Wbf = (ushort_t*)(ws + S + S / 2);    // [1.5S, 2S)

    ushort_t* Wqkv   = Wbf;
    ushort_t* Wproj  = Wbf + 196608;
    ushort_t* Woff   = Wbf + 262144;   // off(64 rows) + aw(32 rows) contiguous
    ushort_t* Waw    = Wbf + 278528;
    ushort_t* Wvproj = Wbf + 286720;
    ushort_t* Woproj = Wbf + 352256;
    ushort_t* Wfc1   = Wbf + 417792;
    ushort_t* Wfc2   = Wbf + 679936;

    ushort_t* QKVbf = (ushort_t*)(ws + 2 * S);              // Q,K,V^T: [2S, 3.5S)
    ushort_t* O1bf  = (ushort_t*)(ws + 2 * S + 3 * S / 2);  // [3.5S, 4S)
    float* Vb   = ws + 2 * S + S / 2;                       // [2.5S, 3.5S)
    float* OffB = ws + 2 * S + 3 * S / 2;                   // [3.5S, 3.75S)
    float* AwB  = OffB + (size_t)BNq * 64;                  // [3.75S, 3.875S)
    ushort_t* Sbbf = (ushort_t*)(AwB + (size_t)BNq * 32);   // [3.875S, 4.375S)
    ushort_t* Valbf = (ushort_t*)(ws + 9 * S / 2);          // [4.5S, 5S)

    auto fp = [&](int i) { return (const float*)d_in[i]; };
    const float* x_in = fp(0);

    // ---- all fp32->bf16 casts in one dispatch ----
    CastArgs ca;
    ca.s[0] = {fp(9),  Wqkv,   192, 196608};
    ca.s[1] = {fp(10), Wproj,  64,  65536};
    ca.s[2] = {fp(12), Woff,   16,  16384};
    ca.s[3] = {fp(14), Waw,    8,   8192};
    ca.s[4] = {fp(16), Wvproj, 64,  65536};
    ca.s[5] = {fp(18), Woproj, 64,  65536};
    ca.s[6] = {fp(20), Wfc1,   256, 262144};
    ca.s[7] = {fp(22), Wfc2,   256, 262144};
    ca.s[8] = {fp(2),  Valbf,  4096, (int)S};
    castm<<<5016, 256, 0, stream>>>(ca);

    // ---- stage 1: self-attention (LN1 fused into qkv lgemm) ----
    lgemm<1, 6, 2><<<512, 256, 0, stream>>>(
        x_in, Wqkv, nullptr, nullptr, fp(3), fp(4), QKVbf);
    attn_mfma<<<dim3(128, 8), 256, 0, stream>>>(
        QKVbf, QKVbf + S, QKVbf + 2 * S, O1bf);
    mgemm<0, false, true, 256><<<dim3(128, 4), 256, 0, stream>>>(
        O1bf, Wproj, fp(11), x_in, X, BNq, 256);

    // ---- stage 2: deformable attention (LN2 fused into off/aw lgemm) ----
    mgemm<0, false, false, 256><<<dim3(128, 4), 256, 0, stream>>>(
        Valbf, Wvproj, fp(17), nullptr, Vb, BNq, 256);
    lgemm<3, 2, 1><<<256, 256, 0, stream>>>(
        X, Woff, fp(13), fp(15), fp(5), fp(6), OffB);
    deform_kernel<<<BNq, 256, 0, stream>>>(fp(1), OffB, AwB, Vb, Sbbf);
    mgemm<0, false, true, 256><<<dim3(128, 4), 256, 0, stream>>>(
        Sbbf, Woproj, fp(19), X, X, BNq, 256);

    // ---- stage 3: MLP (fused ln3+fc1+gelu+fc2+residual; H stays in LDS) ----
    mlp_fused<<<BNq / 32, 256, 0, stream>>>(
        X, Wfc1, fp(21), Wfc2, fp(23), fp(7), fp(8), (float*)d_out);
}